// Round 13
// baseline (150.651 us; speedup 1.0000x reference)
//
#include <hip/hip_runtime.h>

typedef __attribute__((ext_vector_type(8))) short s16x8;
typedef __attribute__((ext_vector_type(4))) float f32x4;

#define MFMA(a, b, c) __builtin_amdgcn_mfma_f32_16x16x32_bf16(a, b, c, 0, 0, 0)

namespace {

constexpr int Bn = 4, Nn = 2048, Hn = 12, Mn = 384;
constexpr float SCALE = 0.35355339059327379f;   // 64^-0.25
constexpr float EPS = 1e-8f;
constexpr float SC2 = 0.51012051755958393f;     // SCALE * log2(e)
constexpr float SQC2 = 0.090169742829486635f;   // 0.5 * SCALE^2 * log2(e)

__device__ inline unsigned short f2b(float f) {
  unsigned u = __builtin_bit_cast(unsigned, f);
  return (unsigned short)((u + 0x7fffu + ((u >> 16) & 1u)) >> 16);
}
__device__ inline float b2f(unsigned short h) {
  unsigned u = ((unsigned)h) << 16;
  return __builtin_bit_cast(float, u);
}

__device__ inline void gl_lds16(const unsigned short* g, unsigned short* l) {
  __builtin_amdgcn_global_load_lds(
      (const __attribute__((address_space(1))) unsigned int*)g,
      (__attribute__((address_space(3))) unsigned int*)l, 16, 0, 0);
}

// 64x64 f32 -> bf16 transpose through LDS (coalesced read AND write)
__device__ inline void tr_cvt_64(const float* __restrict__ src, int sld,
                                 unsigned short* __restrict__ dst, int dld,
                                 float* lds /*[64*65]*/) {
  const int t = threadIdx.x;
  const int r = t >> 4, cq = (t & 15) * 4;
#pragma unroll
  for (int p = 0; p < 4; ++p) {
    const int k = p * 16 + r;
    const float4 v = *(const float4*)(src + (size_t)k * sld + cq);
    lds[k * 65 + cq + 0] = v.x;
    lds[k * 65 + cq + 1] = v.y;
    lds[k * 65 + cq + 2] = v.z;
    lds[k * 65 + cq + 3] = v.w;
  }
  __syncthreads();
  const int n = t >> 2, kq = (t & 3) * 16;
  s16x8 o0, o1;
#pragma unroll
  for (int j = 0; j < 8; ++j) {
    o0[j] = (short)f2b(lds[(kq + j) * 65 + n]);
    o1[j] = (short)f2b(lds[(kq + 8 + j) * 65 + n]);
  }
  *(s16x8*)(dst + (size_t)n * dld + kq) = o0;
  *(s16x8*)(dst + (size_t)n * dld + kq + 8) = o1;
}

// ---------- merged conversion kernel ----------
// grid: [0,3072) cvt_x | [3072,3504) wqT tiles | [3504,3648) wpT tiles | [3648,3720) wtr tiles
__global__ __launch_bounds__(256) void cvt_all_k(const float* __restrict__ x,
                                                 const float* __restrict__ Wqkv,
                                                 const float* __restrict__ Wproj,
                                                 const float* __restrict__ w,
                                                 unsigned short* __restrict__ xb,
                                                 unsigned short* __restrict__ wqT,
                                                 unsigned short* __restrict__ wpT,
                                                 unsigned short* __restrict__ wt) {
  __shared__ float lds[64 * 65];
  const int bid = blockIdx.x;
  if (bid < 3072) {
    const int id = bid * 256 + threadIdx.x;
    const float* src = x + (size_t)id * 8;
    s16x8 o;
#pragma unroll
    for (int j = 0; j < 8; ++j) o[j] = (short)f2b(src[j]);
    *(s16x8*)(xb + (size_t)id * 8) = o;
  } else if (bid < 3504) {  // Wqkv (768 x 2304) -> wqT (2304 x 768); 12 k-tiles x 36 n-tiles
    const int tid = bid - 3072;
    const int k0 = (tid % 12) * 64, n0 = (tid / 12) * 64;
    tr_cvt_64(Wqkv + (size_t)k0 * 2304 + n0, 2304, wqT + (size_t)n0 * 768 + k0, 768, lds);
  } else if (bid < 3648) {  // Wproj (768 x 768) -> wpT (768 x 768); 12 x 12
    const int tid = bid - 3504;
    const int k0 = (tid % 12) * 64, n0 = (tid / 12) * 64;
    tr_cvt_64(Wproj + (size_t)k0 * 768 + n0, 768, wpT + (size_t)n0 * 768 + k0, 768, lds);
  } else {  // w (H,64,384) -> wt (H,384,64); per head 6 m-tiles
    const int tid = bid - 3648;
    const int h = tid / 6, m0 = (tid % 6) * 64;
    tr_cvt_64(w + (size_t)h * 64 * 384 + m0, 384, wt + ((size_t)h * 384 + m0) * 64, 64, lds);
  }
}

// ---------- qkv GEMM: 256x128 tile, 8 waves, 3-buffer depth-2 counted vmcnt ----------
// per K-tile MFMA phase ~1240 CU-cycles > 900-cyc HBM latency -> depth-2 fully covers.
__global__ __launch_bounds__(512) void gemm_qkv_k(const unsigned short* __restrict__ A,
                                                  const unsigned short* __restrict__ Bt,
                                                  unsigned short* __restrict__ obf) {
  __shared__ unsigned short ldsA[3][256 * 64];  // 96KB
  __shared__ unsigned short ldsB[3][128 * 64];  // 48KB
  const int t = threadIdx.x, lane = t & 63, w = t >> 6;
  const int ln = lane & 15, kg = lane >> 4;
  // XCD-aware bijective swizzle: nwg=576, 576%8==0
  const int flat = blockIdx.y * 18 + blockIdx.x;
  const int swz = (flat & 7) * 72 + (flat >> 3);
  const size_t bm = (size_t)(swz / 18) * 256, bn = (size_t)(swz % 18) * 128;
  const int wr = w >> 1, wc = w & 1;  // wave -> 64x64 output quadrant (4M x 2N)
  const int srow = t >> 3, sslot = t & 7;
  f32x4 acc[4][4];
#pragma unroll
  for (int i = 0; i < 4; ++i)
#pragma unroll
    for (int j = 0; j < 4; ++j) acc[i][j] = (f32x4){0.f, 0.f, 0.f, 0.f};

  auto stage = [&](int ti, int d) {  // 6 gl_lds per thread: A0..A3, B0, B1
    const int kb = ti * 64;
#pragma unroll
    for (int i = 0; i < 4; ++i) {
      const int row = i * 64 + srow;
      gl_lds16(A + (bm + row) * 768 + kb + ((sslot ^ (row & 7)) * 8),
               &ldsA[d][i * 4096 + t * 8]);
    }
#pragma unroll
    for (int i = 0; i < 2; ++i) {
      const int row = i * 64 + srow;
      gl_lds16(Bt + (bn + row) * 768 + kb + ((sslot ^ (row & 7)) * 8),
               &ldsB[d][i * 4096 + t * 8]);
    }
  };

  stage(0, 0);
  stage(1, 1);
  for (int ti = 0; ti < 12; ++ti) {
    const int cur = ti % 3;
    if (ti + 2 < 12) {
      stage(ti + 2, (ti + 2) % 3);  // writes buf used by tile ti-1: released at prev end-barrier
      asm volatile("s_waitcnt vmcnt(12)" ::: "memory");  // tile ti's 6 landed (t+1,t+2 in flight)
    } else if (ti == 10) {
      asm volatile("s_waitcnt vmcnt(6)" ::: "memory");
    } else {
      asm volatile("s_waitcnt vmcnt(0)" ::: "memory");
    }
    __builtin_amdgcn_s_barrier();  // all waves' share of tile ti in LDS
    asm volatile("" ::: "memory");
    const char* lA = (const char*)ldsA[cur];
    const char* lB = (const char*)ldsB[cur];
#pragma unroll
    for (int ks = 0; ks < 2; ++ks) {
      s16x8 af[4], bfr[4];
#pragma unroll
      for (int mi = 0; mi < 4; ++mi) {
        const int row = wr * 64 + mi * 16 + ln;
        af[mi] = *(const s16x8*)(lA + row * 128 + (((ks * 4 + kg) ^ (row & 7)) << 4));
      }
#pragma unroll
      for (int ni = 0; ni < 4; ++ni) {
        const int row = wc * 64 + ni * 16 + ln;
        bfr[ni] = *(const s16x8*)(lB + row * 128 + (((ks * 4 + kg) ^ (row & 7)) << 4));
      }
#pragma unroll
      for (int mi = 0; mi < 4; ++mi)
#pragma unroll
        for (int ni = 0; ni < 4; ++ni) acc[mi][ni] = MFMA(af[mi], bfr[ni], acc[mi][ni]);
    }
    asm volatile("" ::: "memory");
    __builtin_amdgcn_s_barrier();  // all waves done reading buf cur -> stage may overwrite
    asm volatile("" ::: "memory");
  }
#pragma unroll
  for (int mi = 0; mi < 4; ++mi)
#pragma unroll
    for (int ni = 0; ni < 4; ++ni) {
      const size_t orow0 = bm + wr * 64 + mi * 16 + kg * 4;
      const size_t ocol = bn + wc * 64 + ni * 16 + ln;
#pragma unroll
      for (int r = 0; r < 4; ++r) obf[(orow0 + r) * 2304 + ocol] = f2b(acc[mi][ni][r]);
    }
}

// ---------- proj GEMM: 128x64 tile (768 blocks -> 3x overlap) + XCD swizzle ----------
__global__ __launch_bounds__(256) void gemm_proj_k(const unsigned short* __restrict__ A,
                                                   const unsigned short* __restrict__ Bt,
                                                   float* __restrict__ out,
                                                   const float* __restrict__ bias) {
  __shared__ unsigned short ldsA[128 * 64];
  __shared__ unsigned short ldsB[64 * 64];
  char* lA = (char*)ldsA;
  char* lB = (char*)ldsB;
  const int t = threadIdx.x, lane = t & 63, w = t >> 6;
  const int ln = lane & 15, kg = lane >> 4;
  // XCD-aware bijective swizzle: nwg=768, 768%8==0
  const int flat = blockIdx.y * 12 + blockIdx.x;
  const int swz = (flat & 7) * 96 + (flat >> 3);
  const size_t bm = (size_t)(swz / 12) * 128, bn = (size_t)(swz % 12) * 64;
  const int wr = w >> 1, wc = w & 1;  // wave -> 64x32 output quadrant
  const int sr = lane >> 3, s = lane & 7;
  f32x4 acc[4][2];
#pragma unroll
  for (int i = 0; i < 4; ++i)
#pragma unroll
    for (int j = 0; j < 2; ++j) acc[i][j] = (f32x4){0.f, 0.f, 0.f, 0.f};

  for (int kb = 0; kb < 768; kb += 64) {
    __syncthreads();
#pragma unroll
    for (int c = 0; c < 4; ++c) {
      const int row = c * 32 + w * 8 + sr;
      const int ss = (s ^ (row & 7)) * 8;
      gl_lds16(A + (bm + row) * 768 + kb + ss, ldsA + (c * 4 + w) * 512);
    }
#pragma unroll
    for (int c = 0; c < 2; ++c) {
      const int row = c * 32 + w * 8 + sr;
      const int ss = (s ^ (row & 7)) * 8;
      gl_lds16(Bt + (bn + row) * 768 + kb + ss, ldsB + (c * 4 + w) * 512);
    }
    __syncthreads();
#pragma unroll
    for (int ks = 0; ks < 2; ++ks) {
      s16x8 af[4], bfr[2];
#pragma unroll
      for (int mi = 0; mi < 4; ++mi) {
        const int row = wr * 64 + mi * 16 + ln;
        af[mi] = *(const s16x8*)(lA + row * 128 + (((ks * 4 + kg) ^ (row & 7)) << 4));
      }
#pragma unroll
      for (int ni = 0; ni < 2; ++ni) {
        const int row = wc * 32 + ni * 16 + ln;
        bfr[ni] = *(const s16x8*)(lB + row * 128 + (((ks * 4 + kg) ^ (row & 7)) << 4));
      }
#pragma unroll
      for (int mi = 0; mi < 4; ++mi)
#pragma unroll
        for (int ni = 0; ni < 2; ++ni) acc[mi][ni] = MFMA(af[mi], bfr[ni], acc[mi][ni]);
    }
  }
#pragma unroll
  for (int mi = 0; mi < 4; ++mi)
#pragma unroll
    for (int ni = 0; ni < 2; ++ni) {
      const size_t orow0 = bm + wr * 64 + mi * 16 + kg * 4;
      const size_t ocol = bn + wc * 32 + ni * 16 + ln;
      const float bv = bias[ocol];
#pragma unroll
      for (int r = 0; r < 4; ++r) out[(orow0 + r) * 768 + ocol] = acc[mi][ni][r] + bv;
    }
}

// ---------- stage 2 helpers ----------
template <int NCT, int CT0>
__device__ inline void s2_gemm2(const char* kfT_b, const char* vt_b, int mts, int ln, int kg,
                                f32x4 (*acc)[3]) {
#pragma unroll
  for (int half = 0; half < 2; ++half) {
    s16x8 a[3], bb[NCT];
#pragma unroll
    for (int j = 0; j < 3; ++j) {
      const int m = (mts + j) * 16 + ln;
      a[j] = *(const s16x8*)(kfT_b + m * 128 + ((half * 64 + kg * 16) ^ ((m & 7) << 4)));
    }
#pragma unroll
    for (int i = 0; i < NCT; ++i) {
      const int c = (CT0 + i) * 16 + ln;
      bb[i] = *(const s16x8*)(vt_b + c * 128 + ((half * 64 + kg * 16) ^ ((c & 7) << 4)));
    }
#pragma unroll
    for (int j = 0; j < 3; ++j)
#pragma unroll
      for (int i = 0; i < NCT; ++i) acc[j][i] = MFMA(a[j], bb[i], acc[j][i]);
  }
}

// ---------- stage 2: phi(k) -> ktv partials (+ksum via ones-column) ----------
// grid (8 = 4 n-groups x 2 m-halves, H, B), 512 threads, 8 chunks of 64 tokens
__global__ __launch_bounds__(512, 4) void stage2_k(const unsigned short* __restrict__ qkv,
                                                   const unsigned short* __restrict__ wt,
                                                   float* __restrict__ ktv_part,
                                                   float* __restrict__ ksum_part) {
  __shared__ unsigned short kfT[192 * 64];     // [m_local][tok] pitch 128B, swizzled
  __shared__ unsigned short vt[2][80 * 64];    // dbuf [c][tok]; row64=1, 65-79=0
  __shared__ unsigned short wt_s[192 * 64];    // [m_local][c] pitch 128B, swizzled
  __shared__ unsigned short k_s[64 * 64];      // [tok][c] pitch 128B, swizzled
  char* kfT_b = (char*)kfT;
  char* wt_b = (char*)wt_s;
  char* k_b = (char*)k_s;
  const int t = threadIdx.x, lane = t & 63, w = t >> 6;
  const int ln = lane & 15, kg = lane >> 4;
  const int gx = blockIdx.x, h = blockIdx.y, b = blockIdx.z;
  const int ng = gx >> 1, mh = gx & 1, m0 = mh * 192;  // ng in [0,4)
  const int bh = b * Hn + h;
  const int ntile = w & 3, mgrp = w >> 2;  // GEMM1 assignment
  const int mts = (w & 3) * 3;             // GEMM2: 3 m-tiles per wave
  const int cg = w >> 2;                   // GEMM2: ctiles {0,1,2} or {3,4}
  const int lr = lane >> 3, sl = lane & 7;

  auto stage_k = [&](int ch) {
    const int row = w * 8 + lr;
    gl_lds16(qkv + ((size_t)b * Nn + ng * 512 + ch * 64 + row) * 2304 + 768 + h * 64 +
                 ((sl ^ (row & 7)) * 8),
             k_s + w * 512);
  };
  const int vn = t >> 3, vc0 = (t & 7) * 8;
  auto load_v = [&](int ch) {
    return *(const s16x8*)(qkv + ((size_t)b * Nn + ng * 512 + ch * 64 + vn) * 2304 + 1536 +
                           h * 64 + vc0);
  };
  auto scat_v = [&](s16x8 vv, int buf) {
    char* vb = (char*)vt[buf];
#pragma unroll
    for (int j = 0; j < 8; ++j) {
      const int c = vc0 + j;
      *(unsigned short*)(vb + c * 128 + ((2 * vn) ^ ((c & 7) << 4))) = (unsigned short)vv[j];
    }
  };

  // ---- prologue: wt tile + vt tail init (both bufs) + chunk 0 k/v
#pragma unroll
  for (int rr = 0; rr < 3; ++rr) {
    const int j = w * 3 + rr;  // 1024-B chunk
    const int row = j * 8 + lr;
    gl_lds16(wt + ((size_t)h * 384 + m0 + row) * 64 + ((sl ^ (row & 7)) * 8), wt_s + j * 512);
  }
  for (int i = t; i < 2048; i += 512) {
    const int buf = i >> 10, r = i & 1023;
    const int c = 64 + (r >> 6), nn = r & 63;
    *(unsigned short*)((char*)vt[buf] + c * 128 + ((2 * nn) ^ ((c & 7) << 4))) =
        (c == 64) ? (unsigned short)0x3F80 : (unsigned short)0;
  }
  stage_k(0);
  s16x8 vreg = load_v(0);
  __syncthreads();  // wt_s, k_s(0) landed; vt tails visible
  scat_v(vreg, 0);
  __syncthreads();  // vt[0] ready

  f32x4 acc[3][3];
#pragma unroll
  for (int j = 0; j < 3; ++j)
#pragma unroll
    for (int i = 0; i < 3; ++i) acc[j][i] = (f32x4){0.f, 0.f, 0.f, 0.f};

  for (int ch = 0; ch < 8; ++ch) {
    {  // GEMM1: proj k -> exp2 -> kfT; sq from A-frags via intra-wave shuffles
      const int arow = ntile * 16 + ln;
      const s16x8 a0 = *(const s16x8*)(k_b + arow * 128 + ((kg ^ (arow & 7)) << 4));
      const s16x8 a1 = *(const s16x8*)(k_b + arow * 128 + (((kg + 4) ^ (arow & 7)) << 4));
      float sq = 0.f;
#pragma unroll
      for (int j = 0; j < 8; ++j) {
        const float f0 = b2f((unsigned short)a0[j]);
        const float f1 = b2f((unsigned short)a1[j]);
        sq = fmaf(f0, f0, sq);
        sq = fmaf(f1, f1, sq);
      }
      sq += __shfl_xor(sq, 16);
      sq += __shfl_xor(sq, 32);  // all lanes: sum_c k[arow][c]^2 (row = ntile*16 + ln)
      const int kg4 = (lane >> 4) << 2;
      float sqv[4];
#pragma unroll
      for (int r = 0; r < 4; ++r) sqv[r] = SQC2 * __shfl(sq, kg4 + r);
#pragma unroll
      for (int i = 0; i < 6; ++i) {
        const int mloc = (mgrp * 6 + i) * 16 + ln;
        const s16x8 b0 = *(const s16x8*)(wt_b + mloc * 128 + ((kg ^ (mloc & 7)) << 4));
        const s16x8 b1 = *(const s16x8*)(wt_b + mloc * 128 + (((kg + 4) ^ (mloc & 7)) << 4));
        f32x4 p = (f32x4){0.f, 0.f, 0.f, 0.f};
        p = MFMA(a0, b0, p);
        p = MFMA(a1, b1, p);
        // ISM dropped: phi_k scale cancels exactly in out = qf*ktv / (qf*ksum)
        const float e0 = exp2f(fmaf(SC2, p[0], -sqv[0]));
        const float e1 = exp2f(fmaf(SC2, p[1], -sqv[1]));
        const float e2 = exp2f(fmaf(SC2, p[2], -sqv[2]));
        const float e3 = exp2f(fmaf(SC2, p[3], -sqv[3]));
        uint2 pk;
        pk.x = (unsigned)f2b(e0) | ((unsigned)f2b(e1) << 16);
        pk.y = (unsigned)f2b(e2) | ((unsigned)f2b(e3) << 16);
        const int bytn = 32 * ntile + 8 * kg;
        *(uint2*)(kfT_b + mloc * 128 + (bytn ^ ((mloc & 7) << 4))) = pk;
      }
    }
    __syncthreads();  // kfT visible; all waves done reading k_s(ch)
    if (ch < 7) {     // issue next chunk's k DMA + v reg-load; hide under GEMM2
      stage_k(ch + 1);
      vreg = load_v(ch + 1);
    }
    const char* vt_cur = (const char*)vt[ch & 1];
    if (cg == 0)
      s2_gemm2<3, 0>(kfT_b, vt_cur, mts, ln, kg, acc);
    else
      s2_gemm2<2, 3>(kfT_b, vt_cur, mts, ln, kg, acc);
    if (ch < 7) scat_v(vreg, (ch + 1) & 1);  // other buffer; overlaps GEMM2 tail
    __syncthreads();  // drains vmcnt: k_s(ch+1) landed; vt[(ch+1)&1] visible
  }
  // write partials
  float* base = ktv_part + ((size_t)ng * 48 + bh) * (384 * 64);
  const int nct2 = cg ? 2 : 3, ct0c = cg ? 3 : 0;
#pragma unroll
  for (int j = 0; j < 3; ++j)
#pragma unroll
    for (int i = 0; i < 3; ++i) {
      if (i >= nct2) continue;
      const int ct = ct0c + i;
      const int mrow0 = m0 + (mts + j) * 16 + kg * 4;
      if (ct < 4) {
        const int c = ct * 16 + ln;
#pragma unroll
        for (int r = 0; r < 4; ++r) base[(size_t)(mrow0 + r) * 64 + c] = acc[j][i][r];
      } else if (ln == 0) {
#pragma unroll
        for (int r = 0; r < 4; ++r)
          ksum_part[((size_t)ng * 48 + bh) * 384 + mrow0 + r] = acc[j][i][r];
      }
    }
}

// ---------- merged reduction over the 4 n-groups -> ktv_ext [bh][80][384] bf16 ----------
// grid: [0,4608) ktv | [4608,4680) ksum hi/lo
__global__ __launch_bounds__(256) void reduce_all_k(const float* __restrict__ part,
                                                    const float* __restrict__ partk,
                                                    unsigned short* __restrict__ ktve) {
  const int bid = blockIdx.x;
  if (bid < 4608) {
    const int bh = bid / 96, chunk = bid % 96;
    const int idx = chunk * 256 + threadIdx.x;
    const int m = idx >> 6, c = idx & 63;
    const size_t o = (size_t)bh * 24576 + idx;
    const size_t gs = (size_t)48 * 24576;
    const float s = part[o] + part[o + gs] + part[o + 2 * gs] + part[o + 3 * gs];
    ktve[((size_t)bh * 80 + c) * 384 + m] = f2b(s);
  } else {
    const int idx = (bid - 4608) * 256 + threadIdx.x;
    const int bh = idx / 384, m = idx % 384;
    const int gk = 48 * 384;
    const float s = partk[idx] + partk[idx + gk] + partk[idx + 2 * gk] + partk[idx + 3 * gk];
    const unsigned short hi = f2b(s);
    const unsigned short lo = f2b(s - b2f(hi));
    const size_t base = ((size_t)bh * 80 + 64) * 384 + m;
    ktve[base] = hi;
    ktve[base + 384] = lo;
  }
}

// ---------- stage 3: fused phi(q)+attn, all staging coalesced ----------
// grid (16, H, B), 512 threads; 128 tokens/block; 6 m-chunks of 64, dbuf wt/ktve
__global__ __launch_bounds__(512, 4) void stage3_k(const unsigned short* __restrict__ qkv,
                                                   const unsigned short* __restrict__ wt,
                                                   const unsigned short* __restrict__ ktve,
                                                   unsigned short* __restrict__ attn) {
  __shared__ unsigned short q_s[128 * 64];      // [tok][c] swizzled, 16KB
  __shared__ unsigned short qf_s[128 * 64];     // [tok][m_chunk] swizzled, wave-private rows
  __shared__ unsigned short wt_s[2][64 * 64];   // [m][c] swizzled, 8KB each
  __shared__ unsigned short kt_s[2][80 * 64];   // [cext][m_chunk] swizzled, 10KB each
  char* q_b = (char*)q_s;
  char* qf_b = (char*)qf_s;
  const int t = threadIdx.x, lane = t & 63, w = t >> 6;
  const int ln = lane & 15, kg = lane >> 4;
  const int nb = blockIdx.x, h = blockIdx.y, b = blockIdx.z, bh = b * Hn + h;
  const size_t tok0 = (size_t)b * Nn + nb * 128;
  const int lr = lane >> 3, sl = lane & 7;

  // stage q tile (128 rows x 128B), 2 gl_lds16 per wave
#pragma unroll
  for (int rr = 0; rr < 2; ++rr) {
    const int row = w * 16 + rr * 8 + lr;
    gl_lds16(qkv + (tok0 + row) * 2304 + h * 64 + ((sl ^ (row & 7)) * 8),
             q_s + (w * 16 + rr * 8) * 64 + lane * 8);
  }
  // chunk stagers
  auto stage_wt = [&](int mc, int pb) {
    const int row = w * 8 + lr;
    gl_lds16(wt + ((size_t)h * 384 + mc * 64 + row) * 64 + ((sl ^ (row & 7)) * 8),
             wt_s[pb] + w * 512 + lane * 8);
  };
  auto stage_kt = [&](int mc, int pb) {
    const int row = w * 8 + lr;
    gl_lds16(ktve + ((size_t)bh * 80 + row) * 384 + mc * 64 + ((sl ^ (row & 7)) * 8),
             kt_s[pb] + w * 512 + lane * 8);
    if (w == 0) {  // only rows 64-71 needed (cols 64=hi,65=lo consumed; rest unread lanes)
      const int row2 = 64 + lr;
      gl_lds16(ktve + ((size_t)bh * 80 + row2) * 384 + mc * 64 + ((sl ^ (row2 & 7)) * 8),
               kt_s[pb] + 64 * 64 + lane * 8);
    }
  };
  stage_wt(0, 0);
  stage_kt(0, 0);
  __syncthreads();  // q + chunk0 ready (barrier drains vmcnt)

  f32x4 acc2[5];
#pragma unroll
  for (int i = 0; i < 5; ++i) acc2[i] = (f32x4){0.f, 0.f, 0.f, 0.f};

  const int arow = w * 16 + ln;          // this wave's A-row (token) for both GEMMs
  const char* qrow = q_b + arow * 128;
  const int asw = (arow & 7) << 4;

  for (int mc = 0; mc < 6; ++mc) {
    const int pb = mc & 1;
    if (mc < 5) {
      stage_wt(mc + 1, pb ^ 1);
      stage_kt(mc + 1, pb ^ 1);
    }
    // GEMM1: proj[tok 16][m 64] for this wave's token tile
    const s16x8 af0 = *(const s16x8*)(qrow + ((kg << 4) ^ asw));
    const s16x8 af1 = *(const s16x8*)(qrow + (((kg + 4) << 4) ^ asw));
    const char* wb = (const char*)wt_s[pb];
    f32x4 p[4];
#pragma unroll
    for (int mt = 0; mt < 4; ++mt) {
      const int mrow = mt * 16 + ln;
      const s16x8 b0 = *(const s16x8*)(wb + mrow * 128 + ((kg ^ (mrow & 7)) << 4));
      const s16x8 b1 = *(const s16x8*)(wb + mrow * 128 + (((kg + 4) ^ (mrow & 7)) << 4));
      f32x4 pp = (f32x4){0.f, 0.f, 0.f, 0.f};
      pp = MFMA(af0, b0, pp);
      p[mt] = MFMA(af1, b1, pp);
    }
    // exp2 -> qf (wave-private rows; sq_q and ISM cancel in num/D)
#pragma unroll
    for (int mt = 0; mt < 4; ++mt) {
#pragma unroll
      for (int r = 0; r < 4; ++r) {
        const int trow = w * 16 + kg * 4 + r;
        const int m = mt * 16 + ln;
        *(unsigned short*)(qf_b + trow * 128 + ((2 * m) ^ ((trow & 7) << 4))) =
            f2b(exp2f(SC2 * p[mt][r]));
      }
    }
    // GEMM2: acc2 += qf(tile) @ kt^T  (same-wave LDS dep only; no barrier)
    const char* qfr = qf_b + arow * 128;
    const s16x8 a0 = *(const s16x8*)(qfr + ((kg << 4) ^ asw));
    const s16x8 a1 = *(const s16x8*)(qfr + (((kg + 4) << 4) ^ asw));
    const char* kb = (const char*)kt_s[pb];
#pragma unroll
    for (int ct = 0; ct < 5; ++ct) {
      const int crow = ct * 16 + ln;
      const s16x8 b0 = *(const s16x8*)(kb + crow * 128 + ((kg ^ (crow & 7)) << 4));
      const s16x8 b1 = *(const s16x8*)(kb + crow * 128 + (((kg + 4) ^ (crow & 7)) << 4));
      acc2[ct] = MFMA(a0, b0, acc2[ct]);
      acc2[ct] = MFMA(a1, b1, acc2[ct]);
    }
    __syncthreads();  // all waves done with buf pb; next stage may overwrite
  }
  // D from c-tile 4 (cols 64=hi, 65=lo) via shuffles; tokens match acc rows
  float dv[4];
#pragma unroll
  for (int r = 0; r < 4; ++r) {
    const float hi = __shfl(acc2[4][r], (lane & 48));
    const float lo = __shfl(acc2[4][r], (lane & 48) | 1);
    dv[r] = 1.0f / (hi + lo + EPS);
  }
#pragma unroll
  for (int ct = 0; ct < 4; ++ct) {
#pragma unroll
    for (int r = 0; r < 4; ++r) {
      const int trow = w * 16 + kg * 4 + r;
      const int c = ct * 16 + ln;
      attn[(tok0 + trow) * 768 + h * 64 + c] = f2b(acc2[ct][r] * dv[r]);
    }
  }
}

}  // namespace

extern "C" void kernel_launch(void* const* d_in, const int* in_sizes, int n_in,
                              void* d_out, int out_size, void* d_ws, size_t ws_size,
                              hipStream_t stream) {
  const float* x = (const float*)d_in[0];
  const float* w = (const float*)d_in[1];
  const float* Wqkv = (const float*)d_in[2];
  const float* Wproj = (const float*)d_in[3];
  const float* bproj = (const float*)d_in[4];

  char* ws = (char*)d_ws;
  // region0 (aliased): [xb 12,582,912 | wqT 3,538,944] vs [ktv_part 18,874,368 | ksum_part 294,912]
  unsigned short* xb = (unsigned short*)(ws);
  unsigned short* wqT = (unsigned short*)(ws + 12582912);
  float* ktv_part = (float*)(ws);
  float* ksum_part = (float*)(ws + 18874368);
  char* p = ws + 19169280;
  unsigned short* qkvb = (unsigned short*)p;  p += 37748736;   // (8192,2304) bf16
  unsigned short* wt = (unsigned short*)p;    p += 589824;     // (12,384,64) bf16
  unsigned short* ktve = (unsigned short*)p;  p += 2949120;    // (48,80,384) bf16
  unsigned short* attn = (unsigned short*)p;  p += 12582912;   // (8192,768) bf16
  unsigned short* wpT = (unsigned short*)p;                    // (768,768) bf16

  cvt_all_k<<<3720, 256, 0, stream>>>(x, Wqkv, Wproj, w, xb, wqT, wpT, wt);
  gemm_qkv_k<<<dim3(18, 32), 512, 0, stream>>>(xb, wqT, qkvb);
  stage2_k<<<dim3(8, 12, 4), 512, 0, stream>>>(qkvb, wt, ktv_part, ksum_part);
  reduce_all_k<<<4680, 256, 0, stream>>>(ktv_part, ksum_part, ktve);
  stage3_k<<<dim3(16, 12, 4), 512, 0, stream>>>(qkvb, wt, ktve, attn);
  gemm_proj_k<<<dim3(12, 64), 256, 0, stream>>>(attn, wpT, (float*)d_out, bproj);
}

// Round 14
// 137.471 us; speedup vs baseline: 1.0959x; 1.0959x over previous
//
#include <hip/hip_runtime.h>

typedef __attribute__((ext_vector_type(8))) short s16x8;
typedef __attribute__((ext_vector_type(4))) float f32x4;

#define MFMA(a, b, c) __builtin_amdgcn_mfma_f32_16x16x32_bf16(a, b, c, 0, 0, 0)

namespace {

constexpr int Bn = 4, Nn = 2048, Hn = 12, Mn = 384;
constexpr float SCALE = 0.35355339059327379f;   // 64^-0.25
constexpr float EPS = 1e-8f;
constexpr float SC2 = 0.51012051755958393f;     // SCALE * log2(e)
constexpr float SQC2 = 0.090169742829486635f;   // 0.5 * SCALE^2 * log2(e)

__device__ inline unsigned short f2b(float f) {
  unsigned u = __builtin_bit_cast(unsigned, f);
  return (unsigned short)((u + 0x7fffu + ((u >> 16) & 1u)) >> 16);
}
__device__ inline float b2f(unsigned short h) {
  unsigned u = ((unsigned)h) << 16;
  return __builtin_bit_cast(float, u);
}

__device__ inline void gl_lds16(const unsigned short* g, unsigned short* l) {
  __builtin_amdgcn_global_load_lds(
      (const __attribute__((address_space(1))) unsigned int*)g,
      (__attribute__((address_space(3))) unsigned int*)l, 16, 0, 0);
}

// 64x64 f32 -> bf16 transpose through LDS (coalesced read AND write)
__device__ inline void tr_cvt_64(const float* __restrict__ src, int sld,
                                 unsigned short* __restrict__ dst, int dld,
                                 float* lds /*[64*65]*/) {
  const int t = threadIdx.x;
  const int r = t >> 4, cq = (t & 15) * 4;
#pragma unroll
  for (int p = 0; p < 4; ++p) {
    const int k = p * 16 + r;
    const float4 v = *(const float4*)(src + (size_t)k * sld + cq);
    lds[k * 65 + cq + 0] = v.x;
    lds[k * 65 + cq + 1] = v.y;
    lds[k * 65 + cq + 2] = v.z;
    lds[k * 65 + cq + 3] = v.w;
  }
  __syncthreads();
  const int n = t >> 2, kq = (t & 3) * 16;
  s16x8 o0, o1;
#pragma unroll
  for (int j = 0; j < 8; ++j) {
    o0[j] = (short)f2b(lds[(kq + j) * 65 + n]);
    o1[j] = (short)f2b(lds[(kq + 8 + j) * 65 + n]);
  }
  *(s16x8*)(dst + (size_t)n * dld + kq) = o0;
  *(s16x8*)(dst + (size_t)n * dld + kq + 8) = o1;
}

// ---------- merged conversion kernel ----------
// grid: [0,3072) cvt_x | [3072,3504) wqT tiles | [3504,3648) wpT tiles | [3648,3720) wtr tiles
__global__ __launch_bounds__(256) void cvt_all_k(const float* __restrict__ x,
                                                 const float* __restrict__ Wqkv,
                                                 const float* __restrict__ Wproj,
                                                 const float* __restrict__ w,
                                                 unsigned short* __restrict__ xb,
                                                 unsigned short* __restrict__ wqT,
                                                 unsigned short* __restrict__ wpT,
                                                 unsigned short* __restrict__ wt) {
  __shared__ float lds[64 * 65];
  const int bid = blockIdx.x;
  if (bid < 3072) {
    const int id = bid * 256 + threadIdx.x;
    const float* src = x + (size_t)id * 8;
    s16x8 o;
#pragma unroll
    for (int j = 0; j < 8; ++j) o[j] = (short)f2b(src[j]);
    *(s16x8*)(xb + (size_t)id * 8) = o;
  } else if (bid < 3504) {  // Wqkv (768 x 2304) -> wqT (2304 x 768); 12 k-tiles x 36 n-tiles
    const int tid = bid - 3072;
    const int k0 = (tid % 12) * 64, n0 = (tid / 12) * 64;
    tr_cvt_64(Wqkv + (size_t)k0 * 2304 + n0, 2304, wqT + (size_t)n0 * 768 + k0, 768, lds);
  } else if (bid < 3648) {  // Wproj (768 x 768) -> wpT (768 x 768); 12 x 12
    const int tid = bid - 3504;
    const int k0 = (tid % 12) * 64, n0 = (tid / 12) * 64;
    tr_cvt_64(Wproj + (size_t)k0 * 768 + n0, 768, wpT + (size_t)n0 * 768 + k0, 768, lds);
  } else {  // w (H,64,384) -> wt (H,384,64); per head 6 m-tiles
    const int tid = bid - 3648;
    const int h = tid / 6, m0 = (tid % 6) * 64;
    tr_cvt_64(w + (size_t)h * 64 * 384 + m0, 384, wt + ((size_t)h * 384 + m0) * 64, 64, lds);
  }
}

// ---------- qkv GEMM: 128x128, single-buffer 2-barrier (m97) + XCD swizzle ----------
// Established optimum for this shape: 32KB LDS -> ~5 blocks/CU; inter-block overlap
// provides the pipelining (r6/r8/r13 A/B: any LDS growth that cuts co-residency loses).
__global__ __launch_bounds__(256) void gemm_qkv_k(const unsigned short* __restrict__ A,
                                                  const unsigned short* __restrict__ Bt,
                                                  unsigned short* __restrict__ obf) {
  __shared__ unsigned short ldsA[128 * 64];
  __shared__ unsigned short ldsB[128 * 64];
  char* lA = (char*)ldsA;
  char* lB = (char*)ldsB;
  const int t = threadIdx.x, lane = t & 63, w = t >> 6;
  const int ln = lane & 15, kg = lane >> 4;
  // XCD-aware bijective swizzle: nwg=1152, 1152%8==0
  const int flat = blockIdx.y * 18 + blockIdx.x;
  const int swz = (flat & 7) * 144 + (flat >> 3);
  const size_t bm = (size_t)(swz / 18) * 128, bn = (size_t)(swz % 18) * 128;
  const int wr = w >> 1, wc = w & 1;
  const int sr = lane >> 3, s = lane & 7;
  f32x4 acc[4][4];
#pragma unroll
  for (int i = 0; i < 4; ++i)
#pragma unroll
    for (int j = 0; j < 4; ++j) acc[i][j] = (f32x4){0.f, 0.f, 0.f, 0.f};

  for (int kb = 0; kb < 768; kb += 64) {
    __syncthreads();  // previous compute done before overwrite
#pragma unroll
    for (int c = 0; c < 4; ++c) {
      const int row = c * 32 + w * 8 + sr;
      const int ss = (s ^ (row & 7)) * 8;  // pre-swizzled global source (rule 21)
      gl_lds16(A + (bm + row) * 768 + kb + ss, ldsA + (c * 4 + w) * 512);
      gl_lds16(Bt + (bn + row) * 768 + kb + ss, ldsB + (c * 4 + w) * 512);
    }
    __syncthreads();  // vmcnt drained at barrier -> tile visible
#pragma unroll
    for (int ks = 0; ks < 2; ++ks) {
      s16x8 af[4], bfr[4];
#pragma unroll
      for (int mi = 0; mi < 4; ++mi) {
        const int row = wr * 64 + mi * 16 + ln;
        af[mi] = *(const s16x8*)(lA + row * 128 + (((ks * 4 + kg) ^ (row & 7)) << 4));
      }
#pragma unroll
      for (int ni = 0; ni < 4; ++ni) {
        const int row = wc * 64 + ni * 16 + ln;
        bfr[ni] = *(const s16x8*)(lB + row * 128 + (((ks * 4 + kg) ^ (row & 7)) << 4));
      }
#pragma unroll
      for (int mi = 0; mi < 4; ++mi)
#pragma unroll
        for (int ni = 0; ni < 4; ++ni) acc[mi][ni] = MFMA(af[mi], bfr[ni], acc[mi][ni]);
    }
  }
#pragma unroll
  for (int mi = 0; mi < 4; ++mi)
#pragma unroll
    for (int ni = 0; ni < 4; ++ni) {
      const size_t orow0 = bm + wr * 64 + mi * 16 + kg * 4;
      const size_t ocol = bn + wc * 64 + ni * 16 + ln;
#pragma unroll
      for (int r = 0; r < 4; ++r) obf[(orow0 + r) * 2304 + ocol] = f2b(acc[mi][ni][r]);
    }
}

// ---------- proj GEMM: 128x64 tile (768 blocks -> 3x overlap) + XCD swizzle ----------
__global__ __launch_bounds__(256) void gemm_proj_k(const unsigned short* __restrict__ A,
                                                   const unsigned short* __restrict__ Bt,
                                                   float* __restrict__ out,
                                                   const float* __restrict__ bias) {
  __shared__ unsigned short ldsA[128 * 64];
  __shared__ unsigned short ldsB[64 * 64];
  char* lA = (char*)ldsA;
  char* lB = (char*)ldsB;
  const int t = threadIdx.x, lane = t & 63, w = t >> 6;
  const int ln = lane & 15, kg = lane >> 4;
  // XCD-aware bijective swizzle: nwg=768, 768%8==0
  const int flat = blockIdx.y * 12 + blockIdx.x;
  const int swz = (flat & 7) * 96 + (flat >> 3);
  const size_t bm = (size_t)(swz / 12) * 128, bn = (size_t)(swz % 12) * 64;
  const int wr = w >> 1, wc = w & 1;  // wave -> 64x32 output quadrant
  const int sr = lane >> 3, s = lane & 7;
  f32x4 acc[4][2];
#pragma unroll
  for (int i = 0; i < 4; ++i)
#pragma unroll
    for (int j = 0; j < 2; ++j) acc[i][j] = (f32x4){0.f, 0.f, 0.f, 0.f};

  for (int kb = 0; kb < 768; kb += 64) {
    __syncthreads();
#pragma unroll
    for (int c = 0; c < 4; ++c) {
      const int row = c * 32 + w * 8 + sr;
      const int ss = (s ^ (row & 7)) * 8;
      gl_lds16(A + (bm + row) * 768 + kb + ss, ldsA + (c * 4 + w) * 512);
    }
#pragma unroll
    for (int c = 0; c < 2; ++c) {
      const int row = c * 32 + w * 8 + sr;
      const int ss = (s ^ (row & 7)) * 8;
      gl_lds16(Bt + (bn + row) * 768 + kb + ss, ldsB + (c * 4 + w) * 512);
    }
    __syncthreads();
#pragma unroll
    for (int ks = 0; ks < 2; ++ks) {
      s16x8 af[4], bfr[2];
#pragma unroll
      for (int mi = 0; mi < 4; ++mi) {
        const int row = wr * 64 + mi * 16 + ln;
        af[mi] = *(const s16x8*)(lA + row * 128 + (((ks * 4 + kg) ^ (row & 7)) << 4));
      }
#pragma unroll
      for (int ni = 0; ni < 2; ++ni) {
        const int row = wc * 32 + ni * 16 + ln;
        bfr[ni] = *(const s16x8*)(lB + row * 128 + (((ks * 4 + kg) ^ (row & 7)) << 4));
      }
#pragma unroll
      for (int mi = 0; mi < 4; ++mi)
#pragma unroll
        for (int ni = 0; ni < 2; ++ni) acc[mi][ni] = MFMA(af[mi], bfr[ni], acc[mi][ni]);
    }
  }
#pragma unroll
  for (int mi = 0; mi < 4; ++mi)
#pragma unroll
    for (int ni = 0; ni < 2; ++ni) {
      const size_t orow0 = bm + wr * 64 + mi * 16 + kg * 4;
      const size_t ocol = bn + wc * 32 + ni * 16 + ln;
      const float bv = bias[ocol];
#pragma unroll
      for (int r = 0; r < 4; ++r) out[(orow0 + r) * 768 + ocol] = acc[mi][ni][r] + bv;
    }
}

// ---------- stage 2 helpers ----------
template <int NCT, int CT0>
__device__ inline void s2_gemm2(const char* kfT_b, const char* vt_b, int mts, int ln, int kg,
                                f32x4 (*acc)[3]) {
#pragma unroll
  for (int half = 0; half < 2; ++half) {
    s16x8 a[3], bb[NCT];
#pragma unroll
    for (int j = 0; j < 3; ++j) {
      const int m = (mts + j) * 16 + ln;
      a[j] = *(const s16x8*)(kfT_b + m * 128 + ((half * 64 + kg * 16) ^ ((m & 7) << 4)));
    }
#pragma unroll
    for (int i = 0; i < NCT; ++i) {
      const int c = (CT0 + i) * 16 + ln;
      bb[i] = *(const s16x8*)(vt_b + c * 128 + ((half * 64 + kg * 16) ^ ((c & 7) << 4)));
    }
#pragma unroll
    for (int j = 0; j < 3; ++j)
#pragma unroll
      for (int i = 0; i < NCT; ++i) acc[j][i] = MFMA(a[j], bb[i], acc[j][i]);
  }
}

// ---------- stage 2: phi(k) -> ktv partials (+ksum via ones-column) ----------
// grid (8 = 4 n-groups x 2 m-halves, H, B), 512 threads, 8 chunks of 64 tokens
__global__ __launch_bounds__(512, 4) void stage2_k(const unsigned short* __restrict__ qkv,
                                                   const unsigned short* __restrict__ wt,
                                                   float* __restrict__ ktv_part,
                                                   float* __restrict__ ksum_part) {
  __shared__ unsigned short kfT[192 * 64];     // [m_local][tok] pitch 128B, swizzled
  __shared__ unsigned short vt[2][80 * 64];    // dbuf [c][tok]; row64=1, 65-79=0
  __shared__ unsigned short wt_s[192 * 64];    // [m_local][c] pitch 128B, swizzled
  __shared__ unsigned short k_s[64 * 64];      // [tok][c] pitch 128B, swizzled
  char* kfT_b = (char*)kfT;
  char* wt_b = (char*)wt_s;
  char* k_b = (char*)k_s;
  const int t = threadIdx.x, lane = t & 63, w = t >> 6;
  const int ln = lane & 15, kg = lane >> 4;
  const int gx = blockIdx.x, h = blockIdx.y, b = blockIdx.z;
  const int ng = gx >> 1, mh = gx & 1, m0 = mh * 192;  // ng in [0,4)
  const int bh = b * Hn + h;
  const int ntile = w & 3, mgrp = w >> 2;  // GEMM1 assignment
  const int mts = (w & 3) * 3;             // GEMM2: 3 m-tiles per wave
  const int cg = w >> 2;                   // GEMM2: ctiles {0,1,2} or {3,4}
  const int lr = lane >> 3, sl = lane & 7;

  auto stage_k = [&](int ch) {
    const int row = w * 8 + lr;
    gl_lds16(qkv + ((size_t)b * Nn + ng * 512 + ch * 64 + row) * 2304 + 768 + h * 64 +
                 ((sl ^ (row & 7)) * 8),
             k_s + w * 512);
  };
  const int vn = t >> 3, vc0 = (t & 7) * 8;
  auto load_v = [&](int ch) {
    return *(const s16x8*)(qkv + ((size_t)b * Nn + ng * 512 + ch * 64 + vn) * 2304 + 1536 +
                           h * 64 + vc0);
  };
  auto scat_v = [&](s16x8 vv, int buf) {
    char* vb = (char*)vt[buf];
#pragma unroll
    for (int j = 0; j < 8; ++j) {
      const int c = vc0 + j;
      *(unsigned short*)(vb + c * 128 + ((2 * vn) ^ ((c & 7) << 4))) = (unsigned short)vv[j];
    }
  };

  // ---- prologue: wt tile + vt tail init (both bufs) + chunk 0 k/v
#pragma unroll
  for (int rr = 0; rr < 3; ++rr) {
    const int j = w * 3 + rr;  // 1024-B chunk
    const int row = j * 8 + lr;
    gl_lds16(wt + ((size_t)h * 384 + m0 + row) * 64 + ((sl ^ (row & 7)) * 8), wt_s + j * 512);
  }
  for (int i = t; i < 2048; i += 512) {
    const int buf = i >> 10, r = i & 1023;
    const int c = 64 + (r >> 6), nn = r & 63;
    *(unsigned short*)((char*)vt[buf] + c * 128 + ((2 * nn) ^ ((c & 7) << 4))) =
        (c == 64) ? (unsigned short)0x3F80 : (unsigned short)0;
  }
  stage_k(0);
  s16x8 vreg = load_v(0);
  __syncthreads();  // wt_s, k_s(0) landed; vt tails visible
  scat_v(vreg, 0);
  __syncthreads();  // vt[0] ready

  f32x4 acc[3][3];
#pragma unroll
  for (int j = 0; j < 3; ++j)
#pragma unroll
    for (int i = 0; i < 3; ++i) acc[j][i] = (f32x4){0.f, 0.f, 0.f, 0.f};

  for (int ch = 0; ch < 8; ++ch) {
    {  // GEMM1: proj k -> exp2 -> kfT; sq from A-frags via intra-wave shuffles
      const int arow = ntile * 16 + ln;
      const s16x8 a0 = *(const s16x8*)(k_b + arow * 128 + ((kg ^ (arow & 7)) << 4));
      const s16x8 a1 = *(const s16x8*)(k_b + arow * 128 + (((kg + 4) ^ (arow & 7)) << 4));
      float sq = 0.f;
#pragma unroll
      for (int j = 0; j < 8; ++j) {
        const float f0 = b2f((unsigned short)a0[j]);
        const float f1 = b2f((unsigned short)a1[j]);
        sq = fmaf(f0, f0, sq);
        sq = fmaf(f1, f1, sq);
      }
      sq += __shfl_xor(sq, 16);
      sq += __shfl_xor(sq, 32);  // all lanes: sum_c k[arow][c]^2 (row = ntile*16 + ln)
      const int kg4 = (lane >> 4) << 2;
      float sqv[4];
#pragma unroll
      for (int r = 0; r < 4; ++r) sqv[r] = SQC2 * __shfl(sq, kg4 + r);
#pragma unroll
      for (int i = 0; i < 6; ++i) {
        const int mloc = (mgrp * 6 + i) * 16 + ln;
        const s16x8 b0 = *(const s16x8*)(wt_b + mloc * 128 + ((kg ^ (mloc & 7)) << 4));
        const s16x8 b1 = *(const s16x8*)(wt_b + mloc * 128 + (((kg + 4) ^ (mloc & 7)) << 4));
        f32x4 p = (f32x4){0.f, 0.f, 0.f, 0.f};
        p = MFMA(a0, b0, p);
        p = MFMA(a1, b1, p);
        // ISM dropped: phi_k scale cancels exactly in out = qf*ktv / (qf*ksum)
        const float e0 = exp2f(fmaf(SC2, p[0], -sqv[0]));
        const float e1 = exp2f(fmaf(SC2, p[1], -sqv[1]));
        const float e2 = exp2f(fmaf(SC2, p[2], -sqv[2]));
        const float e3 = exp2f(fmaf(SC2, p[3], -sqv[3]));
        uint2 pk;
        pk.x = (unsigned)f2b(e0) | ((unsigned)f2b(e1) << 16);
        pk.y = (unsigned)f2b(e2) | ((unsigned)f2b(e3) << 16);
        const int bytn = 32 * ntile + 8 * kg;
        *(uint2*)(kfT_b + mloc * 128 + (bytn ^ ((mloc & 7) << 4))) = pk;
      }
    }
    __syncthreads();  // kfT visible; all waves done reading k_s(ch)
    if (ch < 7) {     // issue next chunk's k DMA + v reg-load; hide under GEMM2
      stage_k(ch + 1);
      vreg = load_v(ch + 1);
    }
    const char* vt_cur = (const char*)vt[ch & 1];
    if (cg == 0)
      s2_gemm2<3, 0>(kfT_b, vt_cur, mts, ln, kg, acc);
    else
      s2_gemm2<2, 3>(kfT_b, vt_cur, mts, ln, kg, acc);
    if (ch < 7) scat_v(vreg, (ch + 1) & 1);  // other buffer; overlaps GEMM2 tail
    __syncthreads();  // drains vmcnt: k_s(ch+1) landed; vt[(ch+1)&1] visible
  }
  // write partials
  float* base = ktv_part + ((size_t)ng * 48 + bh) * (384 * 64);
  const int nct2 = cg ? 2 : 3, ct0c = cg ? 3 : 0;
#pragma unroll
  for (int j = 0; j < 3; ++j)
#pragma unroll
    for (int i = 0; i < 3; ++i) {
      if (i >= nct2) continue;
      const int ct = ct0c + i;
      const int mrow0 = m0 + (mts + j) * 16 + kg * 4;
      if (ct < 4) {
        const int c = ct * 16 + ln;
#pragma unroll
        for (int r = 0; r < 4; ++r) base[(size_t)(mrow0 + r) * 64 + c] = acc[j][i][r];
      } else if (ln == 0) {
#pragma unroll
        for (int r = 0; r < 4; ++r)
          ksum_part[((size_t)ng * 48 + bh) * 384 + mrow0 + r] = acc[j][i][r];
      }
    }
}

// ---------- merged reduction over the 4 n-groups -> ktv_ext [bh][80][384] bf16 ----------
// grid: [0,4608) ktv | [4608,4680) ksum hi/lo
__global__ __launch_bounds__(256) void reduce_all_k(const float* __restrict__ part,
                                                    const float* __restrict__ partk,
                                                    unsigned short* __restrict__ ktve) {
  const int bid = blockIdx.x;
  if (bid < 4608) {
    const int bh = bid / 96, chunk = bid % 96;
    const int idx = chunk * 256 + threadIdx.x;
    const int m = idx >> 6, c = idx & 63;
    const size_t o = (size_t)bh * 24576 + idx;
    const size_t gs = (size_t)48 * 24576;
    const float s = part[o] + part[o + gs] + part[o + 2 * gs] + part[o + 3 * gs];
    ktve[((size_t)bh * 80 + c) * 384 + m] = f2b(s);
  } else {
    const int idx = (bid - 4608) * 256 + threadIdx.x;
    const int bh = idx / 384, m = idx % 384;
    const int gk = 48 * 384;
    const float s = partk[idx] + partk[idx + gk] + partk[idx + 2 * gk] + partk[idx + 3 * gk];
    const unsigned short hi = f2b(s);
    const unsigned short lo = f2b(s - b2f(hi));
    const size_t base = ((size_t)bh * 80 + 64) * 384 + m;
    ktve[base] = hi;
    ktve[base + 384] = lo;
  }
}

// ---------- stage 3: fused phi(q)+attn, all staging coalesced ----------
// grid (16, H, B), 512 threads; 128 tokens/block; 6 m-chunks of 64, dbuf wt/ktve
__global__ __launch_bounds__(512, 4) void stage3_k(const unsigned short* __restrict__ qkv,
                                                   const unsigned short* __restrict__ wt,
                                                   const unsigned short* __restrict__ ktve,
                                                   unsigned short* __restrict__ attn) {
  __shared__ unsigned short q_s[128 * 64];      // [tok][c] swizzled, 16KB
  __shared__ unsigned short qf_s[128 * 64];     // [tok][m_chunk] swizzled, wave-private rows
  __shared__ unsigned short wt_s[2][64 * 64];   // [m][c] swizzled, 8KB each
  __shared__ unsigned short kt_s[2][80 * 64];   // [cext][m_chunk] swizzled, 10KB each
  char* q_b = (char*)q_s;
  char* qf_b = (char*)qf_s;
  const int t = threadIdx.x, lane = t & 63, w = t >> 6;
  const int ln = lane & 15, kg = lane >> 4;
  const int nb = blockIdx.x, h = blockIdx.y, b = blockIdx.z, bh = b * Hn + h;
  const size_t tok0 = (size_t)b * Nn + nb * 128;
  const int lr = lane >> 3, sl = lane & 7;

  // stage q tile (128 rows x 128B), 2 gl_lds16 per wave
#pragma unroll
  for (int rr = 0; rr < 2; ++rr) {
    const int row = w * 16 + rr * 8 + lr;
    gl_lds16(qkv + (tok0 + row) * 2304 + h * 64 + ((sl ^ (row & 7)) * 8),
             q_s + (w * 16 + rr * 8) * 64 + lane * 8);
  }
  // chunk stagers
  auto stage_wt = [&](int mc, int pb) {
    const int row = w * 8 + lr;
    gl_lds16(wt + ((size_t)h * 384 + mc * 64 + row) * 64 + ((sl ^ (row & 7)) * 8),
             wt_s[pb] + w * 512 + lane * 8);
  };
  auto stage_kt = [&](int mc, int pb) {
    const int row = w * 8 + lr;
    gl_lds16(ktve + ((size_t)bh * 80 + row) * 384 + mc * 64 + ((sl ^ (row & 7)) * 8),
             kt_s[pb] + w * 512 + lane * 8);
    if (w == 0) {  // rows 64-71: hi/lo normalizer rows (cols 66-79 unconsumed)
      const int row2 = 64 + lr;
      gl_lds16(ktve + ((size_t)bh * 80 + row2) * 384 + mc * 64 + ((sl ^ (row2 & 7)) * 8),
               kt_s[pb] + 64 * 64 + lane * 8);
    }
  };
  stage_wt(0, 0);
  stage_kt(0, 0);
  __syncthreads();  // q + chunk0 ready (barrier drains vmcnt)

  f32x4 acc2[5];
#pragma unroll
  for (int i = 0; i < 5; ++i) acc2[i] = (f32x4){0.f, 0.f, 0.f, 0.f};

  const int arow = w * 16 + ln;          // this wave's A-row (token) for both GEMMs
  const char* qrow = q_b + arow * 128;
  const int asw = (arow & 7) << 4;

  for (int mc = 0; mc < 6; ++mc) {
    const int pb = mc & 1;
    if (mc < 5) {
      stage_wt(mc + 1, pb ^ 1);
      stage_kt(mc + 1, pb ^ 1);
    }
    // GEMM1: proj[tok 16][m 64] for this wave's token tile
    const s16x8 af0 = *(const s16x8*)(qrow + ((kg << 4) ^ asw));
    const s16x8 af1 = *(const s16x8*)(qrow + (((kg + 4) << 4) ^ asw));
    const char* wb = (const char*)wt_s[pb];
    f32x4 p[4];
#pragma unroll
    for (int mt = 0; mt < 4; ++mt) {
      const int mrow = mt * 16 + ln;
      const s16x8 b0 = *(const s16x8*)(wb + mrow * 128 + ((kg ^ (mrow & 7)) << 4));
      const s16x8 b1 = *(const s16x8*)(wb + mrow * 128 + (((kg + 4) ^ (mrow & 7)) << 4));
      f32x4 pp = (f32x4){0.f, 0.f, 0.f, 0.f};
      pp = MFMA(af0, b0, pp);
      p[mt] = MFMA(af1, b1, pp);
    }
    // exp2 -> qf (wave-private rows; sq_q and ISM cancel in num/D)
#pragma unroll
    for (int mt = 0; mt < 4; ++mt) {
#pragma unroll
      for (int r = 0; r < 4; ++r) {
        const int trow = w * 16 + kg * 4 + r;
        const int m = mt * 16 + ln;
        *(unsigned short*)(qf_b + trow * 128 + ((2 * m) ^ ((trow & 7) << 4))) =
            f2b(exp2f(SC2 * p[mt][r]));
      }
    }
    // GEMM2: acc2 += qf(tile) @ kt^T  (same-wave LDS dep only; no barrier)
    const char* qfr = qf_b + arow * 128;
    const s16x8 a0 = *(const s16x8*)(qfr + ((kg << 4) ^ asw));
    const s16x8 a1 = *(const s16x8*)(qfr + (((kg + 4) << 4) ^ asw));
    const char* kb = (const char*)kt_s[pb];
#pragma unroll
    for (int ct = 0; ct < 5; ++ct) {
      const int crow = ct * 16 + ln;
      const s16x8 b0 = *(const s16x8*)(kb + crow * 128 + ((kg ^ (crow & 7)) << 4));
      const s16x8 b1 = *(const s16x8*)(kb + crow * 128 + (((kg + 4) ^ (crow & 7)) << 4));
      acc2[ct] = MFMA(a0, b0, acc2[ct]);
      acc2[ct] = MFMA(a1, b1, acc2[ct]);
    }
    __syncthreads();  // all waves done with buf pb; next stage may overwrite
  }
  // D from c-tile 4 (cols 64=hi, 65=lo) via shuffles; tokens match acc rows
  float dv[4];
#pragma unroll
  for (int r = 0; r < 4; ++r) {
    const float hi = __shfl(acc2[4][r], (lane & 48));
    const float lo = __shfl(acc2[4][r], (lane & 48) | 1);
    dv[r] = 1.0f / (hi + lo + EPS);
  }
#pragma unroll
  for (int ct = 0; ct < 4; ++ct) {
#pragma unroll
    for (int r = 0; r < 4; ++r) {
      const int trow = w * 16 + kg * 4 + r;
      const int c = ct * 16 + ln;
      attn[(tok0 + trow) * 768 + h * 64 + c] = f2b(acc2[ct][r] * dv[r]);
    }
  }
}

}  // namespace

extern "C" void kernel_launch(void* const* d_in, const int* in_sizes, int n_in,
                              void* d_out, int out_size, void* d_ws, size_t ws_size,
                              hipStream_t stream) {
  const float* x = (const float*)d_in[0];
  const float* w = (const float*)d_in[1];
  const float* Wqkv = (const float*)d_in[2];
  const float* Wproj = (const float*)d_in[3];
  const float* bproj = (const float*)d_in[4];

  char* ws = (char*)d_ws;
  // region0 (aliased): [xb 12,582,912 | wqT 3,538,944] vs [ktv_part 18,874,368 | ksum_part 294,912]
  unsigned short* xb = (unsigned short*)(ws);
  unsigned short* wqT = (unsigned short*)(ws + 12582912);
  float* ktv_part = (float*)(ws);
  float* ksum_part = (float*)(ws + 18874368);
  char* p = ws + 19169280;
  unsigned short* qkvb = (unsigned short*)p;  p += 37748736;   // (8192,2304) bf16
  unsigned short* wt = (unsigned short*)p;    p += 589824;     // (12,384,64) bf16
  unsigned short* ktve = (unsigned short*)p;  p += 2949120;    // (48,80,384) bf16
  unsigned short* attn = (unsigned short*)p;  p += 12582912;   // (8192,768) bf16
  unsigned short* wpT = (unsigned short*)p;                    // (768,768) bf16

  cvt_all_k<<<3720, 256, 0, stream>>>(x, Wqkv, Wproj, w, xb, wqT, wpT, wt);
  gemm_qkv_k<<<dim3(18, 64), 256, 0, stream>>>(xb, wqT, qkvb);
  stage2_k<<<dim3(8, 12, 4), 512, 0, stream>>>(qkvb, wt, ktv_part, ksum_part);
  reduce_all_k<<<4680, 256, 0, stream>>>(ktv_part, ksum_part, ktve);
  stage3_k<<<dim3(16, 12, 4), 512, 0, stream>>>(qkvb, wt, ktve, attn);
  gemm_proj_k<<<dim3(12, 64), 256, 0, stream>>>(attn, wpT, (float*)d_out, bproj);
}

// Round 15
// 131.735 us; speedup vs baseline: 1.1436x; 1.0435x over previous
//
#include <hip/hip_runtime.h>

typedef __attribute__((ext_vector_type(8))) short s16x8;
typedef __attribute__((ext_vector_type(4))) float f32x4;

#define MFMA(a, b, c) __builtin_amdgcn_mfma_f32_16x16x32_bf16(a, b, c, 0, 0, 0)

namespace {

constexpr int Bn = 4, Nn = 2048, Hn = 12, Mn = 384;
constexpr float SCALE = 0.35355339059327379f;   // 64^-0.25
constexpr float EPS = 1e-8f;
constexpr float SC2 = 0.51012051755958393f;     // SCALE * log2(e)
constexpr float SQC2 = 0.090169742829486635f;   // 0.5 * SCALE^2 * log2(e)

__device__ inline unsigned short f2b(float f) {
  unsigned u = __builtin_bit_cast(unsigned, f);
  return (unsigned short)((u + 0x7fffu + ((u >> 16) & 1u)) >> 16);
}
__device__ inline float b2f(unsigned short h) {
  unsigned u = ((unsigned)h) << 16;
  return __builtin_bit_cast(float, u);
}

__device__ inline void gl_lds16(const unsigned short* g, unsigned short* l) {
  __builtin_amdgcn_global_load_lds(
      (const __attribute__((address_space(1))) unsigned int*)g,
      (__attribute__((address_space(3))) unsigned int*)l, 16, 0, 0);
}

// 64x64 f32 -> bf16 transpose through LDS (coalesced read AND write)
__device__ inline void tr_cvt_64(const float* __restrict__ src, int sld,
                                 unsigned short* __restrict__ dst, int dld,
                                 float* lds /*[64*65]*/) {
  const int t = threadIdx.x;
  const int r = t >> 4, cq = (t & 15) * 4;
#pragma unroll
  for (int p = 0; p < 4; ++p) {
    const int k = p * 16 + r;
    const float4 v = *(const float4*)(src + (size_t)k * sld + cq);
    lds[k * 65 + cq + 0] = v.x;
    lds[k * 65 + cq + 1] = v.y;
    lds[k * 65 + cq + 2] = v.z;
    lds[k * 65 + cq + 3] = v.w;
  }
  __syncthreads();
  const int n = t >> 2, kq = (t & 3) * 16;
  s16x8 o0, o1;
#pragma unroll
  for (int j = 0; j < 8; ++j) {
    o0[j] = (short)f2b(lds[(kq + j) * 65 + n]);
    o1[j] = (short)f2b(lds[(kq + 8 + j) * 65 + n]);
  }
  *(s16x8*)(dst + (size_t)n * dld + kq) = o0;
  *(s16x8*)(dst + (size_t)n * dld + kq + 8) = o1;
}

// ---------- merged conversion kernel ----------
// grid: [0,3072) cvt_x | [3072,3504) wqT tiles | [3504,3648) wpT tiles | [3648,3720) wtr tiles
__global__ __launch_bounds__(256) void cvt_all_k(const float* __restrict__ x,
                                                 const float* __restrict__ Wqkv,
                                                 const float* __restrict__ Wproj,
                                                 const float* __restrict__ w,
                                                 unsigned short* __restrict__ xb,
                                                 unsigned short* __restrict__ wqT,
                                                 unsigned short* __restrict__ wpT,
                                                 unsigned short* __restrict__ wt) {
  __shared__ float lds[64 * 65];
  const int bid = blockIdx.x;
  if (bid < 3072) {
    const int id = bid * 256 + threadIdx.x;
    const float* src = x + (size_t)id * 8;
    s16x8 o;
#pragma unroll
    for (int j = 0; j < 8; ++j) o[j] = (short)f2b(src[j]);
    *(s16x8*)(xb + (size_t)id * 8) = o;
  } else if (bid < 3504) {  // Wqkv (768 x 2304) -> wqT (2304 x 768); 12 k-tiles x 36 n-tiles
    const int tid = bid - 3072;
    const int k0 = (tid % 12) * 64, n0 = (tid / 12) * 64;
    tr_cvt_64(Wqkv + (size_t)k0 * 2304 + n0, 2304, wqT + (size_t)n0 * 768 + k0, 768, lds);
  } else if (bid < 3648) {  // Wproj (768 x 768) -> wpT (768 x 768); 12 x 12
    const int tid = bid - 3504;
    const int k0 = (tid % 12) * 64, n0 = (tid / 12) * 64;
    tr_cvt_64(Wproj + (size_t)k0 * 768 + n0, 768, wpT + (size_t)n0 * 768 + k0, 768, lds);
  } else {  // w (H,64,384) -> wt (H,384,64); per head 6 m-tiles
    const int tid = bid - 3648;
    const int h = tid / 6, m0 = (tid % 6) * 64;
    tr_cvt_64(w + (size_t)h * 64 * 384 + m0, 384, wt + ((size_t)h * 384 + m0) * 64, 64, lds);
  }
}

// ---------- qkv GEMM: 128x128, single-buffer 2-barrier (m97) + XCD swizzle ----------
// Established optimum for this shape: 32KB LDS -> ~5 blocks/CU; inter-block overlap
// provides the pipelining (r6/r8/r13 A/B: any LDS growth that cuts co-residency loses).
__global__ __launch_bounds__(256) void gemm_qkv_k(const unsigned short* __restrict__ A,
                                                  const unsigned short* __restrict__ Bt,
                                                  unsigned short* __restrict__ obf) {
  __shared__ unsigned short ldsA[128 * 64];
  __shared__ unsigned short ldsB[128 * 64];
  char* lA = (char*)ldsA;
  char* lB = (char*)ldsB;
  const int t = threadIdx.x, lane = t & 63, w = t >> 6;
  const int ln = lane & 15, kg = lane >> 4;
  // XCD-aware bijective swizzle: nwg=1152, 1152%8==0
  const int flat = blockIdx.y * 18 + blockIdx.x;
  const int swz = (flat & 7) * 144 + (flat >> 3);
  const size_t bm = (size_t)(swz / 18) * 128, bn = (size_t)(swz % 18) * 128;
  const int wr = w >> 1, wc = w & 1;
  const int sr = lane >> 3, s = lane & 7;
  f32x4 acc[4][4];
#pragma unroll
  for (int i = 0; i < 4; ++i)
#pragma unroll
    for (int j = 0; j < 4; ++j) acc[i][j] = (f32x4){0.f, 0.f, 0.f, 0.f};

  for (int kb = 0; kb < 768; kb += 64) {
    __syncthreads();  // previous compute done before overwrite
#pragma unroll
    for (int c = 0; c < 4; ++c) {
      const int row = c * 32 + w * 8 + sr;
      const int ss = (s ^ (row & 7)) * 8;  // pre-swizzled global source (rule 21)
      gl_lds16(A + (bm + row) * 768 + kb + ss, ldsA + (c * 4 + w) * 512);
      gl_lds16(Bt + (bn + row) * 768 + kb + ss, ldsB + (c * 4 + w) * 512);
    }
    __syncthreads();  // vmcnt drained at barrier -> tile visible
#pragma unroll
    for (int ks = 0; ks < 2; ++ks) {
      s16x8 af[4], bfr[4];
#pragma unroll
      for (int mi = 0; mi < 4; ++mi) {
        const int row = wr * 64 + mi * 16 + ln;
        af[mi] = *(const s16x8*)(lA + row * 128 + (((ks * 4 + kg) ^ (row & 7)) << 4));
      }
#pragma unroll
      for (int ni = 0; ni < 4; ++ni) {
        const int row = wc * 64 + ni * 16 + ln;
        bfr[ni] = *(const s16x8*)(lB + row * 128 + (((ks * 4 + kg) ^ (row & 7)) << 4));
      }
#pragma unroll
      for (int mi = 0; mi < 4; ++mi)
#pragma unroll
        for (int ni = 0; ni < 4; ++ni) acc[mi][ni] = MFMA(af[mi], bfr[ni], acc[mi][ni]);
    }
  }
#pragma unroll
  for (int mi = 0; mi < 4; ++mi)
#pragma unroll
    for (int ni = 0; ni < 4; ++ni) {
      const size_t orow0 = bm + wr * 64 + mi * 16 + kg * 4;
      const size_t ocol = bn + wc * 64 + ni * 16 + ln;
#pragma unroll
      for (int r = 0; r < 4; ++r) obf[(orow0 + r) * 2304 + ocol] = f2b(acc[mi][ni][r]);
    }
}

// ---------- proj GEMM: 128x64 tile (768 blocks -> 3x overlap) + XCD swizzle ----------
__global__ __launch_bounds__(256) void gemm_proj_k(const unsigned short* __restrict__ A,
                                                   const unsigned short* __restrict__ Bt,
                                                   float* __restrict__ out,
                                                   const float* __restrict__ bias) {
  __shared__ unsigned short ldsA[128 * 64];
  __shared__ unsigned short ldsB[64 * 64];
  char* lA = (char*)ldsA;
  char* lB = (char*)ldsB;
  const int t = threadIdx.x, lane = t & 63, w = t >> 6;
  const int ln = lane & 15, kg = lane >> 4;
  // XCD-aware bijective swizzle: nwg=768, 768%8==0
  const int flat = blockIdx.y * 12 + blockIdx.x;
  const int swz = (flat & 7) * 96 + (flat >> 3);
  const size_t bm = (size_t)(swz / 12) * 128, bn = (size_t)(swz % 12) * 64;
  const int wr = w >> 1, wc = w & 1;  // wave -> 64x32 output quadrant
  const int sr = lane >> 3, s = lane & 7;
  f32x4 acc[4][2];
#pragma unroll
  for (int i = 0; i < 4; ++i)
#pragma unroll
    for (int j = 0; j < 2; ++j) acc[i][j] = (f32x4){0.f, 0.f, 0.f, 0.f};

  for (int kb = 0; kb < 768; kb += 64) {
    __syncthreads();
#pragma unroll
    for (int c = 0; c < 4; ++c) {
      const int row = c * 32 + w * 8 + sr;
      const int ss = (s ^ (row & 7)) * 8;
      gl_lds16(A + (bm + row) * 768 + kb + ss, ldsA + (c * 4 + w) * 512);
    }
#pragma unroll
    for (int c = 0; c < 2; ++c) {
      const int row = c * 32 + w * 8 + sr;
      const int ss = (s ^ (row & 7)) * 8;
      gl_lds16(Bt + (bn + row) * 768 + kb + ss, ldsB + (c * 4 + w) * 512);
    }
    __syncthreads();
#pragma unroll
    for (int ks = 0; ks < 2; ++ks) {
      s16x8 af[4], bfr[2];
#pragma unroll
      for (int mi = 0; mi < 4; ++mi) {
        const int row = wr * 64 + mi * 16 + ln;
        af[mi] = *(const s16x8*)(lA + row * 128 + (((ks * 4 + kg) ^ (row & 7)) << 4));
      }
#pragma unroll
      for (int ni = 0; ni < 2; ++ni) {
        const int row = wc * 32 + ni * 16 + ln;
        bfr[ni] = *(const s16x8*)(lB + row * 128 + (((ks * 4 + kg) ^ (row & 7)) << 4));
      }
#pragma unroll
      for (int mi = 0; mi < 4; ++mi)
#pragma unroll
        for (int ni = 0; ni < 2; ++ni) acc[mi][ni] = MFMA(af[mi], bfr[ni], acc[mi][ni]);
    }
  }
#pragma unroll
  for (int mi = 0; mi < 4; ++mi)
#pragma unroll
    for (int ni = 0; ni < 2; ++ni) {
      const size_t orow0 = bm + wr * 64 + mi * 16 + kg * 4;
      const size_t ocol = bn + wc * 32 + ni * 16 + ln;
      const float bv = bias[ocol];
#pragma unroll
      for (int r = 0; r < 4; ++r) out[(orow0 + r) * 768 + ocol] = acc[mi][ni][r] + bv;
    }
}

// ---------- stage 2 helpers ----------
template <int NCT, int CT0>
__device__ inline void s2_gemm2(const char* kfT_b, const char* vt_b, int mts, int ln, int kg,
                                f32x4 (*acc)[3]) {
#pragma unroll
  for (int half = 0; half < 2; ++half) {
    s16x8 a[3], bb[NCT];
#pragma unroll
    for (int j = 0; j < 3; ++j) {
      const int m = (mts + j) * 16 + ln;
      a[j] = *(const s16x8*)(kfT_b + m * 128 + ((half * 64 + kg * 16) ^ ((m & 7) << 4)));
    }
#pragma unroll
    for (int i = 0; i < NCT; ++i) {
      const int c = (CT0 + i) * 16 + ln;
      bb[i] = *(const s16x8*)(vt_b + c * 128 + ((half * 64 + kg * 16) ^ ((c & 7) << 4)));
    }
#pragma unroll
    for (int j = 0; j < 3; ++j)
#pragma unroll
      for (int i = 0; i < NCT; ++i) acc[j][i] = MFMA(a[j], bb[i], acc[j][i]);
  }
}

// ---------- stage 2: phi(k) -> ktv partials (+ksum via ones-column) ----------
// grid (8 = 4 n-groups x 2 m-halves, H, B), 512 threads, 8 chunks of 64 tokens
__global__ __launch_bounds__(512, 4) void stage2_k(const unsigned short* __restrict__ qkv,
                                                   const unsigned short* __restrict__ wt,
                                                   float* __restrict__ ktv_part,
                                                   float* __restrict__ ksum_part) {
  __shared__ unsigned short kfT[192 * 64];     // [m_local][tok] pitch 128B, swizzled
  __shared__ unsigned short vt[2][80 * 64];    // dbuf [c][tok]; row64=1, 65-79=0
  __shared__ unsigned short wt_s[192 * 64];    // [m_local][c] pitch 128B, swizzled
  __shared__ unsigned short k_s[64 * 64];      // [tok][c] pitch 128B, swizzled
  char* kfT_b = (char*)kfT;
  char* wt_b = (char*)wt_s;
  char* k_b = (char*)k_s;
  const int t = threadIdx.x, lane = t & 63, w = t >> 6;
  const int ln = lane & 15, kg = lane >> 4;
  const int gx = blockIdx.x, h = blockIdx.y, b = blockIdx.z;
  const int ng = gx >> 1, mh = gx & 1, m0 = mh * 192;  // ng in [0,4)
  const int bh = b * Hn + h;
  const int ntile = w & 3, mgrp = w >> 2;  // GEMM1 assignment
  const int mts = (w & 3) * 3;             // GEMM2: 3 m-tiles per wave
  const int cg = w >> 2;                   // GEMM2: ctiles {0,1,2} or {3,4}
  const int lr = lane >> 3, sl = lane & 7;

  auto stage_k = [&](int ch) {
    const int row = w * 8 + lr;
    gl_lds16(qkv + ((size_t)b * Nn + ng * 512 + ch * 64 + row) * 2304 + 768 + h * 64 +
                 ((sl ^ (row & 7)) * 8),
             k_s + w * 512);
  };
  const int vn = t >> 3, vc0 = (t & 7) * 8;
  auto load_v = [&](int ch) {
    return *(const s16x8*)(qkv + ((size_t)b * Nn + ng * 512 + ch * 64 + vn) * 2304 + 1536 +
                           h * 64 + vc0);
  };
  auto scat_v = [&](s16x8 vv, int buf) {
    char* vb = (char*)vt[buf];
#pragma unroll
    for (int j = 0; j < 8; ++j) {
      const int c = vc0 + j;
      *(unsigned short*)(vb + c * 128 + ((2 * vn) ^ ((c & 7) << 4))) = (unsigned short)vv[j];
    }
  };

  // ---- prologue: wt tile + vt tail init (both bufs) + chunk 0 k/v
#pragma unroll
  for (int rr = 0; rr < 3; ++rr) {
    const int j = w * 3 + rr;  // 1024-B chunk
    const int row = j * 8 + lr;
    gl_lds16(wt + ((size_t)h * 384 + m0 + row) * 64 + ((sl ^ (row & 7)) * 8), wt_s + j * 512);
  }
  for (int i = t; i < 2048; i += 512) {
    const int buf = i >> 10, r = i & 1023;
    const int c = 64 + (r >> 6), nn = r & 63;
    *(unsigned short*)((char*)vt[buf] + c * 128 + ((2 * nn) ^ ((c & 7) << 4))) =
        (c == 64) ? (unsigned short)0x3F80 : (unsigned short)0;
  }
  stage_k(0);
  s16x8 vreg = load_v(0);
  __syncthreads();  // wt_s, k_s(0) landed; vt tails visible
  scat_v(vreg, 0);
  __syncthreads();  // vt[0] ready

  f32x4 acc[3][3];
#pragma unroll
  for (int j = 0; j < 3; ++j)
#pragma unroll
    for (int i = 0; i < 3; ++i) acc[j][i] = (f32x4){0.f, 0.f, 0.f, 0.f};

  for (int ch = 0; ch < 8; ++ch) {
    {  // GEMM1: proj k -> exp2 -> kfT; sq from A-frags via intra-wave shuffles
      const int arow = ntile * 16 + ln;
      const s16x8 a0 = *(const s16x8*)(k_b + arow * 128 + ((kg ^ (arow & 7)) << 4));
      const s16x8 a1 = *(const s16x8*)(k_b + arow * 128 + (((kg + 4) ^ (arow & 7)) << 4));
      float sq = 0.f;
#pragma unroll
      for (int j = 0; j < 8; ++j) {
        const float f0 = b2f((unsigned short)a0[j]);
        const float f1 = b2f((unsigned short)a1[j]);
        sq = fmaf(f0, f0, sq);
        sq = fmaf(f1, f1, sq);
      }
      sq += __shfl_xor(sq, 16);
      sq += __shfl_xor(sq, 32);  // all lanes: sum_c k[arow][c]^2 (row = ntile*16 + ln)
      const int kg4 = (lane >> 4) << 2;
      float sqv[4];
#pragma unroll
      for (int r = 0; r < 4; ++r) sqv[r] = SQC2 * __shfl(sq, kg4 + r);
#pragma unroll
      for (int i = 0; i < 6; ++i) {
        const int mloc = (mgrp * 6 + i) * 16 + ln;
        const s16x8 b0 = *(const s16x8*)(wt_b + mloc * 128 + ((kg ^ (mloc & 7)) << 4));
        const s16x8 b1 = *(const s16x8*)(wt_b + mloc * 128 + (((kg + 4) ^ (mloc & 7)) << 4));
        f32x4 p = (f32x4){0.f, 0.f, 0.f, 0.f};
        p = MFMA(a0, b0, p);
        p = MFMA(a1, b1, p);
        // ISM dropped: phi_k scale cancels exactly in out = qf*ktv / (qf*ksum)
        const float e0 = exp2f(fmaf(SC2, p[0], -sqv[0]));
        const float e1 = exp2f(fmaf(SC2, p[1], -sqv[1]));
        const float e2 = exp2f(fmaf(SC2, p[2], -sqv[2]));
        const float e3 = exp2f(fmaf(SC2, p[3], -sqv[3]));
        uint2 pk;
        pk.x = (unsigned)f2b(e0) | ((unsigned)f2b(e1) << 16);
        pk.y = (unsigned)f2b(e2) | ((unsigned)f2b(e3) << 16);
        const int bytn = 32 * ntile + 8 * kg;
        *(uint2*)(kfT_b + mloc * 128 + (bytn ^ ((mloc & 7) << 4))) = pk;
      }
    }
    __syncthreads();  // kfT visible; all waves done reading k_s(ch)
    if (ch < 7) {     // issue next chunk's k DMA + v reg-load; hide under GEMM2
      stage_k(ch + 1);
      vreg = load_v(ch + 1);
    }
    const char* vt_cur = (const char*)vt[ch & 1];
    if (cg == 0)
      s2_gemm2<3, 0>(kfT_b, vt_cur, mts, ln, kg, acc);
    else
      s2_gemm2<2, 3>(kfT_b, vt_cur, mts, ln, kg, acc);
    if (ch < 7) scat_v(vreg, (ch + 1) & 1);  // other buffer; overlaps GEMM2 tail
    __syncthreads();  // drains vmcnt: k_s(ch+1) landed; vt[(ch+1)&1] visible
  }
  // write partials
  float* base = ktv_part + ((size_t)ng * 48 + bh) * (384 * 64);
  const int nct2 = cg ? 2 : 3, ct0c = cg ? 3 : 0;
#pragma unroll
  for (int j = 0; j < 3; ++j)
#pragma unroll
    for (int i = 0; i < 3; ++i) {
      if (i >= nct2) continue;
      const int ct = ct0c + i;
      const int mrow0 = m0 + (mts + j) * 16 + kg * 4;
      if (ct < 4) {
        const int c = ct * 16 + ln;
#pragma unroll
        for (int r = 0; r < 4; ++r) base[(size_t)(mrow0 + r) * 64 + c] = acc[j][i][r];
      } else if (ln == 0) {
#pragma unroll
        for (int r = 0; r < 4; ++r)
          ksum_part[((size_t)ng * 48 + bh) * 384 + mrow0 + r] = acc[j][i][r];
      }
    }
}

// ---------- reduction over the 4 n-groups -> ktv_ext [bh][80][384] bf16 ----------
// grid: [0,288) ktv 64x64 transpose-reduce tiles | [288,360) ksum hi/lo
// (old version wrote ktve c-major scattered: 64 lines/wave; transpose via LDS fixes it)
__global__ __launch_bounds__(256) void reduce_all_k(const float* __restrict__ part,
                                                    const float* __restrict__ partk,
                                                    unsigned short* __restrict__ ktve) {
  __shared__ float lds[64 * 65];
  const int bid = blockIdx.x;
  const int t = threadIdx.x;
  if (bid < 288) {
    const int bh = bid / 6, m0 = (bid % 6) * 64;
    const size_t gs = (size_t)48 * 24576;
    const int c = t & 63, mr = t >> 6;  // wave-uniform m, lane-contiguous c -> coalesced reads
#pragma unroll
    for (int p = 0; p < 16; ++p) {
      const int m = p * 4 + mr;
      const size_t o = ((size_t)bh * 384 + m0 + m) * 64 + c;
      const float s = part[o] + part[o + gs] + part[o + 2 * gs] + part[o + 3 * gs];
      lds[c * 65 + m] = s;  // (65c+m)%32 = (c+m)%32 -> 2-way max, free
    }
    __syncthreads();
    const int cr = t >> 2, mq = (t & 3) * 16;
    s16x8 o0, o1;
#pragma unroll
    for (int j = 0; j < 8; ++j) {
      o0[j] = (short)f2b(lds[cr * 65 + mq + j]);
      o1[j] = (short)f2b(lds[cr * 65 + mq + 8 + j]);
    }
    unsigned short* dst = ktve + ((size_t)bh * 80 + cr) * 384 + m0 + mq;
    *(s16x8*)dst = o0;          // m-contiguous 32B/lane -> coalesced writes
    *(s16x8*)(dst + 8) = o1;
  } else {
    const int idx = (bid - 288) * 256 + t;  // 48*384
    const int bh = idx / 384, m = idx % 384;
    const int gk = 48 * 384;
    const float s = partk[idx] + partk[idx + gk] + partk[idx + 2 * gk] + partk[idx + 3 * gk];
    const unsigned short hi = f2b(s);
    const unsigned short lo = f2b(s - b2f(hi));
    const size_t base = ((size_t)bh * 80 + 64) * 384 + m;
    ktve[base] = hi;
    ktve[base + 384] = lo;
  }
}

// ---------- stage 3: fused phi(q)+attn, all staging coalesced ----------
// grid (16, H, B), 512 threads; 128 tokens/block; 6 m-chunks of 64, dbuf wt/ktve
__global__ __launch_bounds__(512, 4) void stage3_k(const unsigned short* __restrict__ qkv,
                                                   const unsigned short* __restrict__ wt,
                                                   const unsigned short* __restrict__ ktve,
                                                   unsigned short* __restrict__ attn) {
  __shared__ unsigned short q_s[128 * 64];      // [tok][c] swizzled, 16KB
  __shared__ unsigned short qf_s[128 * 64];     // [tok][m_chunk] swizzled, wave-private rows
  __shared__ unsigned short wt_s[2][64 * 64];   // [m][c] swizzled, 8KB each
  __shared__ unsigned short kt_s[2][80 * 64];   // [cext][m_chunk] swizzled, 10KB each
  char* q_b = (char*)q_s;
  char* qf_b = (char*)qf_s;
  const int t = threadIdx.x, lane = t & 63, w = t >> 6;
  const int ln = lane & 15, kg = lane >> 4;
  const int nb = blockIdx.x, h = blockIdx.y, b = blockIdx.z, bh = b * Hn + h;
  const size_t tok0 = (size_t)b * Nn + nb * 128;
  const int lr = lane >> 3, sl = lane & 7;

  // stage q tile (128 rows x 128B), 2 gl_lds16 per wave
#pragma unroll
  for (int rr = 0; rr < 2; ++rr) {
    const int row = w * 16 + rr * 8 + lr;
    gl_lds16(qkv + (tok0 + row) * 2304 + h * 64 + ((sl ^ (row & 7)) * 8),
             q_s + (w * 16 + rr * 8) * 64 + lane * 8);
  }
  // chunk stagers
  auto stage_wt = [&](int mc, int pb) {
    const int row = w * 8 + lr;
    gl_lds16(wt + ((size_t)h * 384 + mc * 64 + row) * 64 + ((sl ^ (row & 7)) * 8),
             wt_s[pb] + w * 512 + lane * 8);
  };
  auto stage_kt = [&](int mc, int pb) {
    const int row = w * 8 + lr;
    gl_lds16(ktve + ((size_t)bh * 80 + row) * 384 + mc * 64 + ((sl ^ (row & 7)) * 8),
             kt_s[pb] + w * 512 + lane * 8);
    if (w == 0) {  // rows 64-71: hi/lo normalizer rows (cols 66-79 unconsumed)
      const int row2 = 64 + lr;
      gl_lds16(ktve + ((size_t)bh * 80 + row2) * 384 + mc * 64 + ((sl ^ (row2 & 7)) * 8),
               kt_s[pb] + 64 * 64 + lane * 8);
    }
  };
  stage_wt(0, 0);
  stage_kt(0, 0);
  __syncthreads();  // q + chunk0 ready (barrier drains vmcnt)

  f32x4 acc2[5];
#pragma unroll
  for (int i = 0; i < 5; ++i) acc2[i] = (f32x4){0.f, 0.f, 0.f, 0.f};

  const int arow = w * 16 + ln;          // this wave's A-row (token) for both GEMMs
  const char* qrow = q_b + arow * 128;
  const int asw = (arow & 7) << 4;

  for (int mc = 0; mc < 6; ++mc) {
    const int pb = mc & 1;
    if (mc < 5) {
      stage_wt(mc + 1, pb ^ 1);
      stage_kt(mc + 1, pb ^ 1);
    }
    // GEMM1: proj[tok 16][m 64] for this wave's token tile
    const s16x8 af0 = *(const s16x8*)(qrow + ((kg << 4) ^ asw));
    const s16x8 af1 = *(const s16x8*)(qrow + (((kg + 4) << 4) ^ asw));
    const char* wb = (const char*)wt_s[pb];
    f32x4 p[4];
#pragma unroll
    for (int mt = 0; mt < 4; ++mt) {
      const int mrow = mt * 16 + ln;
      const s16x8 b0 = *(const s16x8*)(wb + mrow * 128 + ((kg ^ (mrow & 7)) << 4));
      const s16x8 b1 = *(const s16x8*)(wb + mrow * 128 + (((kg + 4) ^ (mrow & 7)) << 4));
      f32x4 pp = (f32x4){0.f, 0.f, 0.f, 0.f};
      pp = MFMA(af0, b0, pp);
      p[mt] = MFMA(af1, b1, pp);
    }
    // exp2 -> qf (wave-private rows; sq_q and ISM cancel in num/D)
#pragma unroll
    for (int mt = 0; mt < 4; ++mt) {
#pragma unroll
      for (int r = 0; r < 4; ++r) {
        const int trow = w * 16 + kg * 4 + r;
        const int m = mt * 16 + ln;
        *(unsigned short*)(qf_b + trow * 128 + ((2 * m) ^ ((trow & 7) << 4))) =
            f2b(exp2f(SC2 * p[mt][r]));
      }
    }
    // GEMM2: acc2 += qf(tile) @ kt^T  (same-wave LDS dep only; no barrier)
    const char* qfr = qf_b + arow * 128;
    const s16x8 a0 = *(const s16x8*)(qfr + ((kg << 4) ^ asw));
    const s16x8 a1 = *(const s16x8*)(qfr + (((kg + 4) << 4) ^ asw));
    const char* kb = (const char*)kt_s[pb];
#pragma unroll
    for (int ct = 0; ct < 5; ++ct) {
      const int crow = ct * 16 + ln;
      const s16x8 b0 = *(const s16x8*)(kb + crow * 128 + ((kg ^ (crow & 7)) << 4));
      const s16x8 b1 = *(const s16x8*)(kb + crow * 128 + (((kg + 4) ^ (crow & 7)) << 4));
      acc2[ct] = MFMA(a0, b0, acc2[ct]);
      acc2[ct] = MFMA(a1, b1, acc2[ct]);
    }
    __syncthreads();  // all waves done with buf pb; next stage may overwrite
  }
  // D from c-tile 4 (cols 64=hi, 65=lo) via shuffles; tokens match acc rows
  float dv[4];
#pragma unroll
  for (int r = 0; r < 4; ++r) {
    const float hi = __shfl(acc2[4][r], (lane & 48));
    const float lo = __shfl(acc2[4][r], (lane & 48) | 1);
    dv[r] = 1.0f / (hi + lo + EPS);
  }
#pragma unroll
  for (int ct = 0; ct < 4; ++ct) {
#pragma unroll
    for (int r = 0; r < 4; ++r) {
      const int trow = w * 16 + kg * 4 + r;
      const int c = ct * 16 + ln;
      attn[(tok0 + trow) * 768 + h * 64 + c] = f2b(acc2[ct][r] * dv[r]);
    }
  }
}

}  // namespace

extern "C" void kernel_launch(void* const* d_in, const int* in_sizes, int n_in,
                              void* d_out, int out_size, void* d_ws, size_t ws_size,
                              hipStream_t stream) {
  const float* x = (const float*)d_in[0];
  const float* w = (const float*)d_in[1];
  const float* Wqkv = (const float*)d_in[2];
  const float* Wproj = (const float*)d_in[3];
  const float* bproj = (const float*)d_in[4];

  char* ws = (char*)d_ws;
  // region0 (aliased): [xb 12,582,912 | wqT 3,538,944] vs [ktv_part 18,874,368 | ksum_part 294,912]
  unsigned short* xb = (unsigned short*)(ws);
  unsigned short* wqT = (unsigned short*)(ws + 12582912);
  float* ktv_part = (float*)(ws);
  float* ksum_part = (float*)(ws + 18874368);
  char* p = ws + 19169280;
  unsigned short* qkvb = (unsigned short*)p;  p += 37748736;   // (8192,2304) bf16
  unsigned short* wt = (unsigned short*)p;    p += 589824;     // (12,384,64) bf16
  unsigned short* ktve = (unsigned short*)p;  p += 2949120;    // (48,80,384) bf16
  unsigned short* attn = (unsigned short*)p;  p += 12582912;   // (8192,768) bf16
  unsigned short* wpT = (unsigned short*)p;                    // (768,768) bf16

  cvt_all_k<<<3720, 256, 0, stream>>>(x, Wqkv, Wproj, w, xb, wqT, wpT, wt);
  gemm_qkv_k<<<dim3(18, 64), 256, 0, stream>>>(xb, wqT, qkvb);
  stage2_k<<<dim3(8, 12, 4), 512, 0, stream>>>(qkvb, wt, ktv_part, ksum_part);
  reduce_all_k<<<360, 256, 0, stream>>>(ktv_part, ksum_part, ktve);
  stage3_k<<<dim3(16, 12, 4), 512, 0, stream>>>(qkvb, wt, ktve, attn);
  gemm_proj_k<<<dim3(12, 64), 256, 0, stream>>>(attn, wpT, (float*)d_out, bproj);
}

// Round 16
// 130.400 us; speedup vs baseline: 1.1553x; 1.0102x over previous
//
#include <hip/hip_runtime.h>

typedef __attribute__((ext_vector_type(8))) short s16x8;
typedef __attribute__((ext_vector_type(4))) float f32x4;

#define MFMA(a, b, c) __builtin_amdgcn_mfma_f32_16x16x32_bf16(a, b, c, 0, 0, 0)

namespace {

constexpr int Bn = 4, Nn = 2048, Hn = 12, Mn = 384;
constexpr float SCALE = 0.35355339059327379f;   // 64^-0.25
constexpr float EPS = 1e-8f;
constexpr float SC2 = 0.51012051755958393f;     // SCALE * log2(e)
constexpr float SQC2 = 0.090169742829486635f;   // 0.5 * SCALE^2 * log2(e)

__device__ inline unsigned short f2b(float f) {
  unsigned u = __builtin_bit_cast(unsigned, f);
  return (unsigned short)((u + 0x7fffu + ((u >> 16) & 1u)) >> 16);
}
__device__ inline float b2f(unsigned short h) {
  unsigned u = ((unsigned)h) << 16;
  return __builtin_bit_cast(float, u);
}

__device__ inline void gl_lds16(const unsigned short* g, unsigned short* l) {
  __builtin_amdgcn_global_load_lds(
      (const __attribute__((address_space(1))) unsigned int*)g,
      (__attribute__((address_space(3))) unsigned int*)l, 16, 0, 0);
}

// 64x64 f32 -> bf16 transpose through LDS (coalesced read AND write)
__device__ inline void tr_cvt_64(const float* __restrict__ src, int sld,
                                 unsigned short* __restrict__ dst, int dld,
                                 float* lds /*[64*65]*/) {
  const int t = threadIdx.x;
  const int r = t >> 4, cq = (t & 15) * 4;
#pragma unroll
  for (int p = 0; p < 4; ++p) {
    const int k = p * 16 + r;
    const float4 v = *(const float4*)(src + (size_t)k * sld + cq);
    lds[k * 65 + cq + 0] = v.x;
    lds[k * 65 + cq + 1] = v.y;
    lds[k * 65 + cq + 2] = v.z;
    lds[k * 65 + cq + 3] = v.w;
  }
  __syncthreads();
  const int n = t >> 2, kq = (t & 3) * 16;
  s16x8 o0, o1;
#pragma unroll
  for (int j = 0; j < 8; ++j) {
    o0[j] = (short)f2b(lds[(kq + j) * 65 + n]);
    o1[j] = (short)f2b(lds[(kq + 8 + j) * 65 + n]);
  }
  *(s16x8*)(dst + (size_t)n * dld + kq) = o0;
  *(s16x8*)(dst + (size_t)n * dld + kq + 8) = o1;
}

// ---------- merged conversion kernel ----------
// grid: [0,3072) cvt_x | [3072,3504) wqT tiles | [3504,3648) wpT tiles | [3648,3720) wtr tiles
__global__ __launch_bounds__(256) void cvt_all_k(const float* __restrict__ x,
                                                 const float* __restrict__ Wqkv,
                                                 const float* __restrict__ Wproj,
                                                 const float* __restrict__ w,
                                                 unsigned short* __restrict__ xb,
                                                 unsigned short* __restrict__ wqT,
                                                 unsigned short* __restrict__ wpT,
                                                 unsigned short* __restrict__ wt) {
  __shared__ float lds[64 * 65];
  const int bid = blockIdx.x;
  if (bid < 3072) {
    const int id = bid * 256 + threadIdx.x;
    const float* src = x + (size_t)id * 8;
    s16x8 o;
#pragma unroll
    for (int j = 0; j < 8; ++j) o[j] = (short)f2b(src[j]);
    *(s16x8*)(xb + (size_t)id * 8) = o;
  } else if (bid < 3504) {  // Wqkv (768 x 2304) -> wqT (2304 x 768); 12 k-tiles x 36 n-tiles
    const int tid = bid - 3072;
    const int k0 = (tid % 12) * 64, n0 = (tid / 12) * 64;
    tr_cvt_64(Wqkv + (size_t)k0 * 2304 + n0, 2304, wqT + (size_t)n0 * 768 + k0, 768, lds);
  } else if (bid < 3648) {  // Wproj (768 x 768) -> wpT (768 x 768); 12 x 12
    const int tid = bid - 3504;
    const int k0 = (tid % 12) * 64, n0 = (tid / 12) * 64;
    tr_cvt_64(Wproj + (size_t)k0 * 768 + n0, 768, wpT + (size_t)n0 * 768 + k0, 768, lds);
  } else {  // w (H,64,384) -> wt (H,384,64); per head 6 m-tiles
    const int tid = bid - 3648;
    const int h = tid / 6, m0 = (tid % 6) * 64;
    tr_cvt_64(w + (size_t)h * 64 * 384 + m0, 384, wt + ((size_t)h * 384 + m0) * 64, 64, lds);
  }
}

// ---------- qkv GEMM: 128x128, single-buffer 2-barrier (m97) + XCD swizzle ----------
// Established optimum for this shape: 32KB LDS -> ~5 blocks/CU; inter-block overlap
// provides the pipelining (r6/r8/r13 A/B: any LDS growth that cuts co-residency loses).
__global__ __launch_bounds__(256) void gemm_qkv_k(const unsigned short* __restrict__ A,
                                                  const unsigned short* __restrict__ Bt,
                                                  unsigned short* __restrict__ obf) {
  __shared__ unsigned short ldsA[128 * 64];
  __shared__ unsigned short ldsB[128 * 64];
  char* lA = (char*)ldsA;
  char* lB = (char*)ldsB;
  const int t = threadIdx.x, lane = t & 63, w = t >> 6;
  const int ln = lane & 15, kg = lane >> 4;
  // XCD-aware bijective swizzle: nwg=1152, 1152%8==0
  const int flat = blockIdx.y * 18 + blockIdx.x;
  const int swz = (flat & 7) * 144 + (flat >> 3);
  const size_t bm = (size_t)(swz / 18) * 128, bn = (size_t)(swz % 18) * 128;
  const int wr = w >> 1, wc = w & 1;
  const int sr = lane >> 3, s = lane & 7;
  f32x4 acc[4][4];
#pragma unroll
  for (int i = 0; i < 4; ++i)
#pragma unroll
    for (int j = 0; j < 4; ++j) acc[i][j] = (f32x4){0.f, 0.f, 0.f, 0.f};

  for (int kb = 0; kb < 768; kb += 64) {
    __syncthreads();  // previous compute done before overwrite
#pragma unroll
    for (int c = 0; c < 4; ++c) {
      const int row = c * 32 + w * 8 + sr;
      const int ss = (s ^ (row & 7)) * 8;  // pre-swizzled global source (rule 21)
      gl_lds16(A + (bm + row) * 768 + kb + ss, ldsA + (c * 4 + w) * 512);
      gl_lds16(Bt + (bn + row) * 768 + kb + ss, ldsB + (c * 4 + w) * 512);
    }
    __syncthreads();  // vmcnt drained at barrier -> tile visible
#pragma unroll
    for (int ks = 0; ks < 2; ++ks) {
      s16x8 af[4], bfr[4];
#pragma unroll
      for (int mi = 0; mi < 4; ++mi) {
        const int row = wr * 64 + mi * 16 + ln;
        af[mi] = *(const s16x8*)(lA + row * 128 + (((ks * 4 + kg) ^ (row & 7)) << 4));
      }
#pragma unroll
      for (int ni = 0; ni < 4; ++ni) {
        const int row = wc * 64 + ni * 16 + ln;
        bfr[ni] = *(const s16x8*)(lB + row * 128 + (((ks * 4 + kg) ^ (row & 7)) << 4));
      }
#pragma unroll
      for (int mi = 0; mi < 4; ++mi)
#pragma unroll
        for (int ni = 0; ni < 4; ++ni) acc[mi][ni] = MFMA(af[mi], bfr[ni], acc[mi][ni]);
    }
  }
#pragma unroll
  for (int mi = 0; mi < 4; ++mi)
#pragma unroll
    for (int ni = 0; ni < 4; ++ni) {
      const size_t orow0 = bm + wr * 64 + mi * 16 + kg * 4;
      const size_t ocol = bn + wc * 64 + ni * 16 + ln;
#pragma unroll
      for (int r = 0; r < 4; ++r) obf[(orow0 + r) * 2304 + ocol] = f2b(acc[mi][ni][r]);
    }
}

// ---------- proj GEMM: 128x64 tile (768 blocks -> 3x overlap) + XCD swizzle ----------
__global__ __launch_bounds__(256) void gemm_proj_k(const unsigned short* __restrict__ A,
                                                   const unsigned short* __restrict__ Bt,
                                                   float* __restrict__ out,
                                                   const float* __restrict__ bias) {
  __shared__ unsigned short ldsA[128 * 64];
  __shared__ unsigned short ldsB[64 * 64];
  char* lA = (char*)ldsA;
  char* lB = (char*)ldsB;
  const int t = threadIdx.x, lane = t & 63, w = t >> 6;
  const int ln = lane & 15, kg = lane >> 4;
  // XCD-aware bijective swizzle: nwg=768, 768%8==0
  const int flat = blockIdx.y * 12 + blockIdx.x;
  const int swz = (flat & 7) * 96 + (flat >> 3);
  const size_t bm = (size_t)(swz / 12) * 128, bn = (size_t)(swz % 12) * 64;
  const int wr = w >> 1, wc = w & 1;  // wave -> 64x32 output quadrant
  const int sr = lane >> 3, s = lane & 7;
  f32x4 acc[4][2];
#pragma unroll
  for (int i = 0; i < 4; ++i)
#pragma unroll
    for (int j = 0; j < 2; ++j) acc[i][j] = (f32x4){0.f, 0.f, 0.f, 0.f};

  for (int kb = 0; kb < 768; kb += 64) {
    __syncthreads();
#pragma unroll
    for (int c = 0; c < 4; ++c) {
      const int row = c * 32 + w * 8 + sr;
      const int ss = (s ^ (row & 7)) * 8;
      gl_lds16(A + (bm + row) * 768 + kb + ss, ldsA + (c * 4 + w) * 512);
    }
#pragma unroll
    for (int c = 0; c < 2; ++c) {
      const int row = c * 32 + w * 8 + sr;
      const int ss = (s ^ (row & 7)) * 8;
      gl_lds16(Bt + (bn + row) * 768 + kb + ss, ldsB + (c * 4 + w) * 512);
    }
    __syncthreads();
#pragma unroll
    for (int ks = 0; ks < 2; ++ks) {
      s16x8 af[4], bfr[2];
#pragma unroll
      for (int mi = 0; mi < 4; ++mi) {
        const int row = wr * 64 + mi * 16 + ln;
        af[mi] = *(const s16x8*)(lA + row * 128 + (((ks * 4 + kg) ^ (row & 7)) << 4));
      }
#pragma unroll
      for (int ni = 0; ni < 2; ++ni) {
        const int row = wc * 32 + ni * 16 + ln;
        bfr[ni] = *(const s16x8*)(lB + row * 128 + (((ks * 4 + kg) ^ (row & 7)) << 4));
      }
#pragma unroll
      for (int mi = 0; mi < 4; ++mi)
#pragma unroll
        for (int ni = 0; ni < 2; ++ni) acc[mi][ni] = MFMA(af[mi], bfr[ni], acc[mi][ni]);
    }
  }
#pragma unroll
  for (int mi = 0; mi < 4; ++mi)
#pragma unroll
    for (int ni = 0; ni < 2; ++ni) {
      const size_t orow0 = bm + wr * 64 + mi * 16 + kg * 4;
      const size_t ocol = bn + wc * 32 + ni * 16 + ln;
      const float bv = bias[ocol];
#pragma unroll
      for (int r = 0; r < 4; ++r) out[(orow0 + r) * 768 + ocol] = acc[mi][ni][r] + bv;
    }
}

// ---------- stage 2 helpers ----------
template <int NCT, int CT0>
__device__ inline void s2_gemm2(const char* kfT_b, const char* vt_b, int mts, int ln, int kg,
                                f32x4 (*acc)[3]) {
#pragma unroll
  for (int half = 0; half < 2; ++half) {
    s16x8 a[3], bb[NCT];
#pragma unroll
    for (int j = 0; j < 3; ++j) {
      const int m = (mts + j) * 16 + ln;
      a[j] = *(const s16x8*)(kfT_b + m * 128 + ((half * 64 + kg * 16) ^ ((m & 7) << 4)));
    }
#pragma unroll
    for (int i = 0; i < NCT; ++i) {
      const int c = (CT0 + i) * 16 + ln;
      bb[i] = *(const s16x8*)(vt_b + c * 128 + ((half * 64 + kg * 16) ^ ((c & 7) << 4)));
    }
#pragma unroll
    for (int j = 0; j < 3; ++j)
#pragma unroll
      for (int i = 0; i < NCT; ++i) acc[j][i] = MFMA(a[j], bb[i], acc[j][i]);
  }
}

// ---------- stage 2: phi(k) -> ktv partials (+ksum via ones-column) ----------
// grid (16 = 8 n-groups x 2 m-halves, H, B), 512 threads, 4 chunks of 64 tokens
// (768 blocks = 3/CU occupancy vs 1.5 at 4 groups; reduce is now cheap/coalesced)
__global__ __launch_bounds__(512, 4) void stage2_k(const unsigned short* __restrict__ qkv,
                                                   const unsigned short* __restrict__ wt,
                                                   float* __restrict__ ktv_part,
                                                   float* __restrict__ ksum_part) {
  __shared__ unsigned short kfT[192 * 64];     // [m_local][tok] pitch 128B, swizzled
  __shared__ unsigned short vt[2][80 * 64];    // dbuf [c][tok]; row64=1, 65-79=0
  __shared__ unsigned short wt_s[192 * 64];    // [m_local][c] pitch 128B, swizzled
  __shared__ unsigned short k_s[64 * 64];      // [tok][c] pitch 128B, swizzled
  char* kfT_b = (char*)kfT;
  char* wt_b = (char*)wt_s;
  char* k_b = (char*)k_s;
  const int t = threadIdx.x, lane = t & 63, w = t >> 6;
  const int ln = lane & 15, kg = lane >> 4;
  const int gx = blockIdx.x, h = blockIdx.y, b = blockIdx.z;
  const int ng = gx >> 1, mh = gx & 1, m0 = mh * 192;  // ng in [0,8)
  const int bh = b * Hn + h;
  const int ntile = w & 3, mgrp = w >> 2;  // GEMM1 assignment
  const int mts = (w & 3) * 3;             // GEMM2: 3 m-tiles per wave
  const int cg = w >> 2;                   // GEMM2: ctiles {0,1,2} or {3,4}
  const int lr = lane >> 3, sl = lane & 7;

  auto stage_k = [&](int ch) {
    const int row = w * 8 + lr;
    gl_lds16(qkv + ((size_t)b * Nn + ng * 256 + ch * 64 + row) * 2304 + 768 + h * 64 +
                 ((sl ^ (row & 7)) * 8),
             k_s + w * 512);
  };
  const int vn = t >> 3, vc0 = (t & 7) * 8;
  auto load_v = [&](int ch) {
    return *(const s16x8*)(qkv + ((size_t)b * Nn + ng * 256 + ch * 64 + vn) * 2304 + 1536 +
                           h * 64 + vc0);
  };
  auto scat_v = [&](s16x8 vv, int buf) {
    char* vb = (char*)vt[buf];
#pragma unroll
    for (int j = 0; j < 8; ++j) {
      const int c = vc0 + j;
      *(unsigned short*)(vb + c * 128 + ((2 * vn) ^ ((c & 7) << 4))) = (unsigned short)vv[j];
    }
  };

  // ---- prologue: wt tile + vt tail init (both bufs) + chunk 0 k/v
#pragma unroll
  for (int rr = 0; rr < 3; ++rr) {
    const int j = w * 3 + rr;  // 1024-B chunk
    const int row = j * 8 + lr;
    gl_lds16(wt + ((size_t)h * 384 + m0 + row) * 64 + ((sl ^ (row & 7)) * 8), wt_s + j * 512);
  }
  for (int i = t; i < 2048; i += 512) {
    const int buf = i >> 10, r = i & 1023;
    const int c = 64 + (r >> 6), nn = r & 63;
    *(unsigned short*)((char*)vt[buf] + c * 128 + ((2 * nn) ^ ((c & 7) << 4))) =
        (c == 64) ? (unsigned short)0x3F80 : (unsigned short)0;
  }
  stage_k(0);
  s16x8 vreg = load_v(0);
  __syncthreads();  // wt_s, k_s(0) landed; vt tails visible
  scat_v(vreg, 0);
  __syncthreads();  // vt[0] ready

  f32x4 acc[3][3];
#pragma unroll
  for (int j = 0; j < 3; ++j)
#pragma unroll
    for (int i = 0; i < 3; ++i) acc[j][i] = (f32x4){0.f, 0.f, 0.f, 0.f};

  for (int ch = 0; ch < 4; ++ch) {
    {  // GEMM1: proj k -> exp2 -> kfT; sq from A-frags via intra-wave shuffles
      const int arow = ntile * 16 + ln;
      const s16x8 a0 = *(const s16x8*)(k_b + arow * 128 + ((kg ^ (arow & 7)) << 4));
      const s16x8 a1 = *(const s16x8*)(k_b + arow * 128 + (((kg + 4) ^ (arow & 7)) << 4));
      float sq = 0.f;
#pragma unroll
      for (int j = 0; j < 8; ++j) {
        const float f0 = b2f((unsigned short)a0[j]);
        const float f1 = b2f((unsigned short)a1[j]);
        sq = fmaf(f0, f0, sq);
        sq = fmaf(f1, f1, sq);
      }
      sq += __shfl_xor(sq, 16);
      sq += __shfl_xor(sq, 32);  // all lanes: sum_c k[arow][c]^2 (row = ntile*16 + ln)
      const int kg4 = (lane >> 4) << 2;
      float sqv[4];
#pragma unroll
      for (int r = 0; r < 4; ++r) sqv[r] = SQC2 * __shfl(sq, kg4 + r);
#pragma unroll
      for (int i = 0; i < 6; ++i) {
        const int mloc = (mgrp * 6 + i) * 16 + ln;
        const s16x8 b0 = *(const s16x8*)(wt_b + mloc * 128 + ((kg ^ (mloc & 7)) << 4));
        const s16x8 b1 = *(const s16x8*)(wt_b + mloc * 128 + (((kg + 4) ^ (mloc & 7)) << 4));
        f32x4 p = (f32x4){0.f, 0.f, 0.f, 0.f};
        p = MFMA(a0, b0, p);
        p = MFMA(a1, b1, p);
        // ISM dropped: phi_k scale cancels exactly in out = qf*ktv / (qf*ksum)
        const float e0 = exp2f(fmaf(SC2, p[0], -sqv[0]));
        const float e1 = exp2f(fmaf(SC2, p[1], -sqv[1]));
        const float e2 = exp2f(fmaf(SC2, p[2], -sqv[2]));
        const float e3 = exp2f(fmaf(SC2, p[3], -sqv[3]));
        uint2 pk;
        pk.x = (unsigned)f2b(e0) | ((unsigned)f2b(e1) << 16);
        pk.y = (unsigned)f2b(e2) | ((unsigned)f2b(e3) << 16);
        const int bytn = 32 * ntile + 8 * kg;
        *(uint2*)(kfT_b + mloc * 128 + (bytn ^ ((mloc & 7) << 4))) = pk;
      }
    }
    __syncthreads();  // kfT visible; all waves done reading k_s(ch)
    if (ch < 3) {     // issue next chunk's k DMA + v reg-load; hide under GEMM2
      stage_k(ch + 1);
      vreg = load_v(ch + 1);
    }
    const char* vt_cur = (const char*)vt[ch & 1];
    if (cg == 0)
      s2_gemm2<3, 0>(kfT_b, vt_cur, mts, ln, kg, acc);
    else
      s2_gemm2<2, 3>(kfT_b, vt_cur, mts, ln, kg, acc);
    if (ch < 3) scat_v(vreg, (ch + 1) & 1);  // other buffer; overlaps GEMM2 tail
    __syncthreads();  // drains vmcnt: k_s(ch+1) landed; vt[(ch+1)&1] visible
  }
  // write partials
  float* base = ktv_part + ((size_t)ng * 48 + bh) * (384 * 64);
  const int nct2 = cg ? 2 : 3, ct0c = cg ? 3 : 0;
#pragma unroll
  for (int j = 0; j < 3; ++j)
#pragma unroll
    for (int i = 0; i < 3; ++i) {
      if (i >= nct2) continue;
      const int ct = ct0c + i;
      const int mrow0 = m0 + (mts + j) * 16 + kg * 4;
      if (ct < 4) {
        const int c = ct * 16 + ln;
#pragma unroll
        for (int r = 0; r < 4; ++r) base[(size_t)(mrow0 + r) * 64 + c] = acc[j][i][r];
      } else if (ln == 0) {
#pragma unroll
        for (int r = 0; r < 4; ++r)
          ksum_part[((size_t)ng * 48 + bh) * 384 + mrow0 + r] = acc[j][i][r];
      }
    }
}

// ---------- reduction over the 8 n-groups -> ktv_ext [bh][80][384] bf16 ----------
// grid: [0,288) ktv 64x64 transpose-reduce tiles | [288,360) ksum hi/lo
__global__ __launch_bounds__(256) void reduce_all_k(const float* __restrict__ part,
                                                    const float* __restrict__ partk,
                                                    unsigned short* __restrict__ ktve) {
  __shared__ float lds[64 * 65];
  const int bid = blockIdx.x;
  const int t = threadIdx.x;
  if (bid < 288) {
    const int bh = bid / 6, m0 = (bid % 6) * 64;
    const size_t gs = (size_t)48 * 24576;
    const int c = t & 63, mr = t >> 6;  // wave-uniform m, lane-contiguous c -> coalesced reads
#pragma unroll
    for (int p = 0; p < 16; ++p) {
      const int m = p * 4 + mr;
      const size_t o = ((size_t)bh * 384 + m0 + m) * 64 + c;
      float s = 0.f;
#pragma unroll
      for (int g = 0; g < 8; ++g) s += part[o + (size_t)g * gs];
      lds[c * 65 + m] = s;  // (65c+m)%32 = (c+m)%32 -> 2-way max, free
    }
    __syncthreads();
    const int cr = t >> 2, mq = (t & 3) * 16;
    s16x8 o0, o1;
#pragma unroll
    for (int j = 0; j < 8; ++j) {
      o0[j] = (short)f2b(lds[cr * 65 + mq + j]);
      o1[j] = (short)f2b(lds[cr * 65 + mq + 8 + j]);
    }
    unsigned short* dst = ktve + ((size_t)bh * 80 + cr) * 384 + m0 + mq;
    *(s16x8*)dst = o0;          // m-contiguous 32B/lane -> coalesced writes
    *(s16x8*)(dst + 8) = o1;
  } else {
    const int idx = (bid - 288) * 256 + t;  // 48*384
    const int bh = idx / 384, m = idx % 384;
    const int gk = 48 * 384;
    float s = 0.f;
#pragma unroll
    for (int g = 0; g < 8; ++g) s += partk[idx + g * gk];
    const unsigned short hi = f2b(s);
    const unsigned short lo = f2b(s - b2f(hi));
    const size_t base = ((size_t)bh * 80 + 64) * 384 + m;
    ktve[base] = hi;
    ktve[base + 384] = lo;
  }
}

// ---------- stage 3: fused phi(q)+attn, all staging coalesced ----------
// grid (16, H, B), 512 threads; 128 tokens/block; 6 m-chunks of 64, dbuf wt/ktve
__global__ __launch_bounds__(512, 4) void stage3_k(const unsigned short* __restrict__ qkv,
                                                   const unsigned short* __restrict__ wt,
                                                   const unsigned short* __restrict__ ktve,
                                                   unsigned short* __restrict__ attn) {
  __shared__ unsigned short q_s[128 * 64];      // [tok][c] swizzled, 16KB
  __shared__ unsigned short qf_s[128 * 64];     // [tok][m_chunk] swizzled, wave-private rows
  __shared__ unsigned short wt_s[2][64 * 64];   // [m][c] swizzled, 8KB each
  __shared__ unsigned short kt_s[2][80 * 64];   // [cext][m_chunk] swizzled, 10KB each
  char* q_b = (char*)q_s;
  char* qf_b = (char*)qf_s;
  const int t = threadIdx.x, lane = t & 63, w = t >> 6;
  const int ln = lane & 15, kg = lane >> 4;
  const int nb = blockIdx.x, h = blockIdx.y, b = blockIdx.z, bh = b * Hn + h;
  const size_t tok0 = (size_t)b * Nn + nb * 128;
  const int lr = lane >> 3, sl = lane & 7;

  // stage q tile (128 rows x 128B), 2 gl_lds16 per wave
#pragma unroll
  for (int rr = 0; rr < 2; ++rr) {
    const int row = w * 16 + rr * 8 + lr;
    gl_lds16(qkv + (tok0 + row) * 2304 + h * 64 + ((sl ^ (row & 7)) * 8),
             q_s + (w * 16 + rr * 8) * 64 + lane * 8);
  }
  // chunk stagers
  auto stage_wt = [&](int mc, int pb) {
    const int row = w * 8 + lr;
    gl_lds16(wt + ((size_t)h * 384 + mc * 64 + row) * 64 + ((sl ^ (row & 7)) * 8),
             wt_s[pb] + w * 512 + lane * 8);
  };
  auto stage_kt = [&](int mc, int pb) {
    const int row = w * 8 + lr;
    gl_lds16(ktve + ((size_t)bh * 80 + row) * 384 + mc * 64 + ((sl ^ (row & 7)) * 8),
             kt_s[pb] + w * 512 + lane * 8);
    if (w == 0) {  // rows 64-71: hi/lo normalizer rows (cols 66-79 unconsumed)
      const int row2 = 64 + lr;
      gl_lds16(ktve + ((size_t)bh * 80 + row2) * 384 + mc * 64 + ((sl ^ (row2 & 7)) * 8),
               kt_s[pb] + 64 * 64 + lane * 8);
    }
  };
  stage_wt(0, 0);
  stage_kt(0, 0);
  __syncthreads();  // q + chunk0 ready (barrier drains vmcnt)

  f32x4 acc2[5];
#pragma unroll
  for (int i = 0; i < 5; ++i) acc2[i] = (f32x4){0.f, 0.f, 0.f, 0.f};

  const int arow = w * 16 + ln;          // this wave's A-row (token) for both GEMMs
  const char* qrow = q_b + arow * 128;
  const int asw = (arow & 7) << 4;

  for (int mc = 0; mc < 6; ++mc) {
    const int pb = mc & 1;
    if (mc < 5) {
      stage_wt(mc + 1, pb ^ 1);
      stage_kt(mc + 1, pb ^ 1);
    }
    // GEMM1: proj[tok 16][m 64] for this wave's token tile
    const s16x8 af0 = *(const s16x8*)(qrow + ((kg << 4) ^ asw));
    const s16x8 af1 = *(const s16x8*)(qrow + (((kg + 4) << 4) ^ asw));
    const char* wb = (const char*)wt_s[pb];
    f32x4 p[4];
#pragma unroll
    for (int mt = 0; mt < 4; ++mt) {
      const int mrow = mt * 16 + ln;
      const s16x8 b0 = *(const s16x8*)(wb + mrow * 128 + ((kg ^ (mrow & 7)) << 4));
      const s16x8 b1 = *(const s16x8*)(wb + mrow * 128 + (((kg + 4) ^ (mrow & 7)) << 4));
      f32x4 pp = (f32x4){0.f, 0.f, 0.f, 0.f};
      pp = MFMA(af0, b0, pp);
      p[mt] = MFMA(af1, b1, pp);
    }
    // exp2 -> qf (wave-private rows; sq_q and ISM cancel in num/D)
#pragma unroll
    for (int mt = 0; mt < 4; ++mt) {
#pragma unroll
      for (int r = 0; r < 4; ++r) {
        const int trow = w * 16 + kg * 4 + r;
        const int m = mt * 16 + ln;
        *(unsigned short*)(qf_b + trow * 128 + ((2 * m) ^ ((trow & 7) << 4))) =
            f2b(exp2f(SC2 * p[mt][r]));
      }
    }
    // GEMM2: acc2 += qf(tile) @ kt^T  (same-wave LDS dep only; no barrier)
    const char* qfr = qf_b + arow * 128;
    const s16x8 a0 = *(const s16x8*)(qfr + ((kg << 4) ^ asw));
    const s16x8 a1 = *(const s16x8*)(qfr + (((kg + 4) << 4) ^ asw));
    const char* kb = (const char*)kt_s[pb];
#pragma unroll
    for (int ct = 0; ct < 5; ++ct) {
      const int crow = ct * 16 + ln;
      const s16x8 b0 = *(const s16x8*)(kb + crow * 128 + ((kg ^ (crow & 7)) << 4));
      const s16x8 b1 = *(const s16x8*)(kb + crow * 128 + (((kg + 4) ^ (crow & 7)) << 4));
      acc2[ct] = MFMA(a0, b0, acc2[ct]);
      acc2[ct] = MFMA(a1, b1, acc2[ct]);
    }
    __syncthreads();  // all waves done with buf pb; next stage may overwrite
  }
  // D from c-tile 4 (cols 64=hi, 65=lo) via shuffles; tokens match acc rows
  float dv[4];
#pragma unroll
  for (int r = 0; r < 4; ++r) {
    const float hi = __shfl(acc2[4][r], (lane & 48));
    const float lo = __shfl(acc2[4][r], (lane & 48) | 1);
    dv[r] = 1.0f / (hi + lo + EPS);
  }
#pragma unroll
  for (int ct = 0; ct < 4; ++ct) {
#pragma unroll
    for (int r = 0; r < 4; ++r) {
      const int trow = w * 16 + kg * 4 + r;
      const int c = ct * 16 + ln;
      attn[(tok0 + trow) * 768 + h * 64 + c] = f2b(acc2[ct][r] * dv[r]);
    }
  }
}

}  // namespace

extern "C" void kernel_launch(void* const* d_in, const int* in_sizes, int n_in,
                              void* d_out, int out_size, void* d_ws, size_t ws_size,
                              hipStream_t stream) {
  const float* x = (const float*)d_in[0];
  const float* w = (const float*)d_in[1];
  const float* Wqkv = (const float*)d_in[2];
  const float* Wproj = (const float*)d_in[3];
  const float* bproj = (const float*)d_in[4];

  char* ws = (char*)d_ws;
  // region0 (aliased): [xb 12,582,912 | wqT 3,538,944] vs [ktv_part 37,748,736 | ksum_part 589,824]
  unsigned short* xb = (unsigned short*)(ws);
  unsigned short* wqT = (unsigned short*)(ws + 12582912);
  float* ktv_part = (float*)(ws);
  float* ksum_part = (float*)(ws + 37748736);
  char* p = ws + 38338560;
  unsigned short* qkvb = (unsigned short*)p;  p += 37748736;   // (8192,2304) bf16
  unsigned short* wt = (unsigned short*)p;    p += 589824;     // (12,384,64) bf16
  unsigned short* ktve = (unsigned short*)p;  p += 2949120;    // (48,80,384) bf16
  unsigned short* attn = (unsigned short*)p;  p += 12582912;   // (8192,768) bf16
  unsigned short* wpT = (unsigned short*)p;                    // (768,768) bf16

  cvt_all_k<<<3720, 256, 0, stream>>>(x, Wqkv, Wproj, w, xb, wqT, wpT, wt);
  gemm_qkv_k<<<dim3(18, 64), 256, 0, stream>>>(xb, wqT, qkvb);
  stage2_k<<<dim3(16, 12, 4), 512, 0, stream>>>(qkvb, wt, ktv_part, ksum_part);
  reduce_all_k<<<360, 256, 0, stream>>>(ktv_part, ksum_part, ktve);
  stage3_k<<<dim3(16, 12, 4), 512, 0, stream>>>(qkvb, wt, ktve, attn);
  gemm_proj_k<<<dim3(12, 64), 256, 0, stream>>>(attn, wpT, (float*)d_out, bproj);
}

// Round 17
// 129.616 us; speedup vs baseline: 1.1623x; 1.0060x over previous
//
#include <hip/hip_runtime.h>

typedef __attribute__((ext_vector_type(8))) short s16x8;
typedef __attribute__((ext_vector_type(4))) float f32x4;

#define MFMA(a, b, c) __builtin_amdgcn_mfma_f32_16x16x32_bf16(a, b, c, 0, 0, 0)

namespace {

constexpr int Bn = 4, Nn = 2048, Hn = 12, Mn = 384;
constexpr float SCALE = 0.35355339059327379f;   // 64^-0.25
constexpr float EPS = 1e-8f;
constexpr float SC2 = 0.51012051755958393f;     // SCALE * log2(e)
constexpr float SQC2 = 0.090169742829486635f;   // 0.5 * SCALE^2 * log2(e)

__device__ inline unsigned short f2b(float f) {
  unsigned u = __builtin_bit_cast(unsigned, f);
  return (unsigned short)((u + 0x7fffu + ((u >> 16) & 1u)) >> 16);
}
__device__ inline float b2f(unsigned short h) {
  unsigned u = ((unsigned)h) << 16;
  return __builtin_bit_cast(float, u);
}

__device__ inline void gl_lds16(const unsigned short* g, unsigned short* l) {
  __builtin_amdgcn_global_load_lds(
      (const __attribute__((address_space(1))) unsigned int*)g,
      (__attribute__((address_space(3))) unsigned int*)l, 16, 0, 0);
}

// 64x64 f32 -> bf16 transpose through LDS (coalesced read AND write)
__device__ inline void tr_cvt_64(const float* __restrict__ src, int sld,
                                 unsigned short* __restrict__ dst, int dld,
                                 float* lds /*[64*65]*/) {
  const int t = threadIdx.x;
  const int r = t >> 4, cq = (t & 15) * 4;
#pragma unroll
  for (int p = 0; p < 4; ++p) {
    const int k = p * 16 + r;
    const float4 v = *(const float4*)(src + (size_t)k * sld + cq);
    lds[k * 65 + cq + 0] = v.x;
    lds[k * 65 + cq + 1] = v.y;
    lds[k * 65 + cq + 2] = v.z;
    lds[k * 65 + cq + 3] = v.w;
  }
  __syncthreads();
  const int n = t >> 2, kq = (t & 3) * 16;
  s16x8 o0, o1;
#pragma unroll
  for (int j = 0; j < 8; ++j) {
    o0[j] = (short)f2b(lds[(kq + j) * 65 + n]);
    o1[j] = (short)f2b(lds[(kq + 8 + j) * 65 + n]);
  }
  *(s16x8*)(dst + (size_t)n * dld + kq) = o0;
  *(s16x8*)(dst + (size_t)n * dld + kq + 8) = o1;
}

// ---------- merged conversion kernel ----------
// grid: [0,3072) cvt_x | [3072,3504) wqT tiles | [3504,3648) wpT tiles | [3648,3720) wtr tiles
__global__ __launch_bounds__(256) void cvt_all_k(const float* __restrict__ x,
                                                 const float* __restrict__ Wqkv,
                                                 const float* __restrict__ Wproj,
                                                 const float* __restrict__ w,
                                                 unsigned short* __restrict__ xb,
                                                 unsigned short* __restrict__ wqT,
                                                 unsigned short* __restrict__ wpT,
                                                 unsigned short* __restrict__ wt) {
  __shared__ float lds[64 * 65];
  const int bid = blockIdx.x;
  if (bid < 3072) {
    const int id = bid * 256 + threadIdx.x;
    const float* src = x + (size_t)id * 8;
    s16x8 o;
#pragma unroll
    for (int j = 0; j < 8; ++j) o[j] = (short)f2b(src[j]);
    *(s16x8*)(xb + (size_t)id * 8) = o;
  } else if (bid < 3504) {  // Wqkv (768 x 2304) -> wqT (2304 x 768); 12 k-tiles x 36 n-tiles
    const int tid = bid - 3072;
    const int k0 = (tid % 12) * 64, n0 = (tid / 12) * 64;
    tr_cvt_64(Wqkv + (size_t)k0 * 2304 + n0, 2304, wqT + (size_t)n0 * 768 + k0, 768, lds);
  } else if (bid < 3648) {  // Wproj (768 x 768) -> wpT (768 x 768); 12 x 12
    const int tid = bid - 3504;
    const int k0 = (tid % 12) * 64, n0 = (tid / 12) * 64;
    tr_cvt_64(Wproj + (size_t)k0 * 768 + n0, 768, wpT + (size_t)n0 * 768 + k0, 768, lds);
  } else {  // w (H,64,384) -> wt (H,384,64); per head 6 m-tiles
    const int tid = bid - 3648;
    const int h = tid / 6, m0 = (tid % 6) * 64;
    tr_cvt_64(w + (size_t)h * 64 * 384 + m0, 384, wt + ((size_t)h * 384 + m0) * 64, 64, lds);
  }
}

// ---------- qkv GEMM: 128x128, single-buffer 2-barrier (m97) + XCD swizzle ----------
// Established optimum for this shape: 32KB LDS -> ~5 blocks/CU; inter-block overlap
// provides the pipelining (r6/r8/r13 A/B: any LDS growth that cuts co-residency loses).
__global__ __launch_bounds__(256) void gemm_qkv_k(const unsigned short* __restrict__ A,
                                                  const unsigned short* __restrict__ Bt,
                                                  unsigned short* __restrict__ obf) {
  __shared__ unsigned short ldsA[128 * 64];
  __shared__ unsigned short ldsB[128 * 64];
  char* lA = (char*)ldsA;
  char* lB = (char*)ldsB;
  const int t = threadIdx.x, lane = t & 63, w = t >> 6;
  const int ln = lane & 15, kg = lane >> 4;
  // XCD-aware bijective swizzle: nwg=1152, 1152%8==0
  const int flat = blockIdx.y * 18 + blockIdx.x;
  const int swz = (flat & 7) * 144 + (flat >> 3);
  const size_t bm = (size_t)(swz / 18) * 128, bn = (size_t)(swz % 18) * 128;
  const int wr = w >> 1, wc = w & 1;
  const int sr = lane >> 3, s = lane & 7;
  f32x4 acc[4][4];
#pragma unroll
  for (int i = 0; i < 4; ++i)
#pragma unroll
    for (int j = 0; j < 4; ++j) acc[i][j] = (f32x4){0.f, 0.f, 0.f, 0.f};

  for (int kb = 0; kb < 768; kb += 64) {
    __syncthreads();  // previous compute done before overwrite
#pragma unroll
    for (int c = 0; c < 4; ++c) {
      const int row = c * 32 + w * 8 + sr;
      const int ss = (s ^ (row & 7)) * 8;  // pre-swizzled global source (rule 21)
      gl_lds16(A + (bm + row) * 768 + kb + ss, ldsA + (c * 4 + w) * 512);
      gl_lds16(Bt + (bn + row) * 768 + kb + ss, ldsB + (c * 4 + w) * 512);
    }
    __syncthreads();  // vmcnt drained at barrier -> tile visible
#pragma unroll
    for (int ks = 0; ks < 2; ++ks) {
      s16x8 af[4], bfr[4];
#pragma unroll
      for (int mi = 0; mi < 4; ++mi) {
        const int row = wr * 64 + mi * 16 + ln;
        af[mi] = *(const s16x8*)(lA + row * 128 + (((ks * 4 + kg) ^ (row & 7)) << 4));
      }
#pragma unroll
      for (int ni = 0; ni < 4; ++ni) {
        const int row = wc * 64 + ni * 16 + ln;
        bfr[ni] = *(const s16x8*)(lB + row * 128 + (((ks * 4 + kg) ^ (row & 7)) << 4));
      }
#pragma unroll
      for (int mi = 0; mi < 4; ++mi)
#pragma unroll
        for (int ni = 0; ni < 4; ++ni) acc[mi][ni] = MFMA(af[mi], bfr[ni], acc[mi][ni]);
    }
  }
#pragma unroll
  for (int mi = 0; mi < 4; ++mi)
#pragma unroll
    for (int ni = 0; ni < 4; ++ni) {
      const size_t orow0 = bm + wr * 64 + mi * 16 + kg * 4;
      const size_t ocol = bn + wc * 64 + ni * 16 + ln;
#pragma unroll
      for (int r = 0; r < 4; ++r) obf[(orow0 + r) * 2304 + ocol] = f2b(acc[mi][ni][r]);
    }
}

// ---------- proj GEMM: 128x64 tile (768 blocks -> 3x overlap) + XCD swizzle ----------
__global__ __launch_bounds__(256) void gemm_proj_k(const unsigned short* __restrict__ A,
                                                   const unsigned short* __restrict__ Bt,
                                                   float* __restrict__ out,
                                                   const float* __restrict__ bias) {
  __shared__ unsigned short ldsA[128 * 64];
  __shared__ unsigned short ldsB[64 * 64];
  char* lA = (char*)ldsA;
  char* lB = (char*)ldsB;
  const int t = threadIdx.x, lane = t & 63, w = t >> 6;
  const int ln = lane & 15, kg = lane >> 4;
  // XCD-aware bijective swizzle: nwg=768, 768%8==0
  const int flat = blockIdx.y * 12 + blockIdx.x;
  const int swz = (flat & 7) * 96 + (flat >> 3);
  const size_t bm = (size_t)(swz / 12) * 128, bn = (size_t)(swz % 12) * 64;
  const int wr = w >> 1, wc = w & 1;  // wave -> 64x32 output quadrant
  const int sr = lane >> 3, s = lane & 7;
  f32x4 acc[4][2];
#pragma unroll
  for (int i = 0; i < 4; ++i)
#pragma unroll
    for (int j = 0; j < 2; ++j) acc[i][j] = (f32x4){0.f, 0.f, 0.f, 0.f};

  for (int kb = 0; kb < 768; kb += 64) {
    __syncthreads();
#pragma unroll
    for (int c = 0; c < 4; ++c) {
      const int row = c * 32 + w * 8 + sr;
      const int ss = (s ^ (row & 7)) * 8;
      gl_lds16(A + (bm + row) * 768 + kb + ss, ldsA + (c * 4 + w) * 512);
    }
#pragma unroll
    for (int c = 0; c < 2; ++c) {
      const int row = c * 32 + w * 8 + sr;
      const int ss = (s ^ (row & 7)) * 8;
      gl_lds16(Bt + (bn + row) * 768 + kb + ss, ldsB + (c * 4 + w) * 512);
    }
    __syncthreads();
#pragma unroll
    for (int ks = 0; ks < 2; ++ks) {
      s16x8 af[4], bfr[2];
#pragma unroll
      for (int mi = 0; mi < 4; ++mi) {
        const int row = wr * 64 + mi * 16 + ln;
        af[mi] = *(const s16x8*)(lA + row * 128 + (((ks * 4 + kg) ^ (row & 7)) << 4));
      }
#pragma unroll
      for (int ni = 0; ni < 2; ++ni) {
        const int row = wc * 32 + ni * 16 + ln;
        bfr[ni] = *(const s16x8*)(lB + row * 128 + (((ks * 4 + kg) ^ (row & 7)) << 4));
      }
#pragma unroll
      for (int mi = 0; mi < 4; ++mi)
#pragma unroll
        for (int ni = 0; ni < 2; ++ni) acc[mi][ni] = MFMA(af[mi], bfr[ni], acc[mi][ni]);
    }
  }
#pragma unroll
  for (int mi = 0; mi < 4; ++mi)
#pragma unroll
    for (int ni = 0; ni < 2; ++ni) {
      const size_t orow0 = bm + wr * 64 + mi * 16 + kg * 4;
      const size_t ocol = bn + wc * 32 + ni * 16 + ln;
      const float bv = bias[ocol];
#pragma unroll
      for (int r = 0; r < 4; ++r) out[(orow0 + r) * 768 + ocol] = acc[mi][ni][r] + bv;
    }
}

// ---------- stage 2 helpers ----------
template <int NCT, int CT0>
__device__ inline void s2_gemm2(const char* kfT_b, const char* vt_b, int mts, int ln, int kg,
                                f32x4 (*acc)[3]) {
#pragma unroll
  for (int half = 0; half < 2; ++half) {
    s16x8 a[3], bb[NCT];
#pragma unroll
    for (int j = 0; j < 3; ++j) {
      const int m = (mts + j) * 16 + ln;
      a[j] = *(const s16x8*)(kfT_b + m * 128 + ((half * 64 + kg * 16) ^ ((m & 7) << 4)));
    }
#pragma unroll
    for (int i = 0; i < NCT; ++i) {
      const int c = (CT0 + i) * 16 + ln;
      bb[i] = *(const s16x8*)(vt_b + c * 128 + ((half * 64 + kg * 16) ^ ((c & 7) << 4)));
    }
#pragma unroll
    for (int j = 0; j < 3; ++j)
#pragma unroll
      for (int i = 0; i < NCT; ++i) acc[j][i] = MFMA(a[j], bb[i], acc[j][i]);
  }
}

// ---------- stage 2: phi(k) -> ktv partials (+ksum via ones-column) ----------
// grid (16 = 8 n-groups x 2 m-halves, H, B), 512 threads, 4 chunks of 64 tokens
__global__ __launch_bounds__(512, 4) void stage2_k(const unsigned short* __restrict__ qkv,
                                                   const unsigned short* __restrict__ wt,
                                                   float* __restrict__ ktv_part,
                                                   float* __restrict__ ksum_part) {
  __shared__ unsigned short kfT[192 * 64];     // [m_local][tok] pitch 128B, swizzled
  __shared__ unsigned short vt[2][80 * 64];    // dbuf [c][tok]; row64=1, 65-79=0
  __shared__ unsigned short wt_s[192 * 64];    // [m_local][c] pitch 128B, swizzled
  __shared__ unsigned short k_s[64 * 64];      // [tok][c] pitch 128B, swizzled
  char* kfT_b = (char*)kfT;
  char* wt_b = (char*)wt_s;
  char* k_b = (char*)k_s;
  const int t = threadIdx.x, lane = t & 63, w = t >> 6;
  const int ln = lane & 15, kg = lane >> 4;
  const int gx = blockIdx.x, h = blockIdx.y, b = blockIdx.z;
  const int ng = gx >> 1, mh = gx & 1, m0 = mh * 192;  // ng in [0,8)
  const int bh = b * Hn + h;
  const int ntile = w & 3, mgrp = w >> 2;  // GEMM1 assignment
  const int mts = (w & 3) * 3;             // GEMM2: 3 m-tiles per wave
  const int cg = w >> 2;                   // GEMM2: ctiles {0,1,2} or {3,4}
  const int lr = lane >> 3, sl = lane & 7;

  auto stage_k = [&](int ch) {
    const int row = w * 8 + lr;
    gl_lds16(qkv + ((size_t)b * Nn + ng * 256 + ch * 64 + row) * 2304 + 768 + h * 64 +
                 ((sl ^ (row & 7)) * 8),
             k_s + w * 512);
  };
  const int vn = t >> 3, vc0 = (t & 7) * 8;
  auto load_v = [&](int ch) {
    return *(const s16x8*)(qkv + ((size_t)b * Nn + ng * 256 + ch * 64 + vn) * 2304 + 1536 +
                           h * 64 + vc0);
  };
  auto scat_v = [&](s16x8 vv, int buf) {
    char* vb = (char*)vt[buf];
#pragma unroll
    for (int j = 0; j < 8; ++j) {
      const int c = vc0 + j;
      *(unsigned short*)(vb + c * 128 + ((2 * vn) ^ ((c & 7) << 4))) = (unsigned short)vv[j];
    }
  };

  // ---- prologue: wt tile + vt tail init (both bufs) + chunk 0 k/v
#pragma unroll
  for (int rr = 0; rr < 3; ++rr) {
    const int j = w * 3 + rr;  // 1024-B chunk
    const int row = j * 8 + lr;
    gl_lds16(wt + ((size_t)h * 384 + m0 + row) * 64 + ((sl ^ (row & 7)) * 8), wt_s + j * 512);
  }
  for (int i = t; i < 2048; i += 512) {
    const int buf = i >> 10, r = i & 1023;
    const int c = 64 + (r >> 6), nn = r & 63;
    *(unsigned short*)((char*)vt[buf] + c * 128 + ((2 * nn) ^ ((c & 7) << 4))) =
        (c == 64) ? (unsigned short)0x3F80 : (unsigned short)0;
  }
  stage_k(0);
  scat_v(load_v(0), 0);  // vt[0] c<64: disjoint from tail-init (c>=64) and DMA dests
  __syncthreads();       // wt_s, k_s(0) landed; vt[0] complete & visible
  s16x8 vreg;

  f32x4 acc[3][3];
#pragma unroll
  for (int j = 0; j < 3; ++j)
#pragma unroll
    for (int i = 0; i < 3; ++i) acc[j][i] = (f32x4){0.f, 0.f, 0.f, 0.f};

  for (int ch = 0; ch < 4; ++ch) {
    {  // GEMM1: proj k -> exp2 -> kfT; sq from A-frags via intra-wave shuffles
      const int arow = ntile * 16 + ln;
      const s16x8 a0 = *(const s16x8*)(k_b + arow * 128 + ((kg ^ (arow & 7)) << 4));
      const s16x8 a1 = *(const s16x8*)(k_b + arow * 128 + (((kg + 4) ^ (arow & 7)) << 4));
      float sq = 0.f;
#pragma unroll
      for (int j = 0; j < 8; ++j) {
        const float f0 = b2f((unsigned short)a0[j]);
        const float f1 = b2f((unsigned short)a1[j]);
        sq = fmaf(f0, f0, sq);
        sq = fmaf(f1, f1, sq);
      }
      sq += __shfl_xor(sq, 16);
      sq += __shfl_xor(sq, 32);  // all lanes: sum_c k[arow][c]^2 (row = ntile*16 + ln)
      const int kg4 = (lane >> 4) << 2;
      float sqv[4];
#pragma unroll
      for (int r = 0; r < 4; ++r) sqv[r] = SQC2 * __shfl(sq, kg4 + r);
#pragma unroll
      for (int i = 0; i < 6; ++i) {
        const int mloc = (mgrp * 6 + i) * 16 + ln;
        const s16x8 b0 = *(const s16x8*)(wt_b + mloc * 128 + ((kg ^ (mloc & 7)) << 4));
        const s16x8 b1 = *(const s16x8*)(wt_b + mloc * 128 + (((kg + 4) ^ (mloc & 7)) << 4));
        f32x4 p = (f32x4){0.f, 0.f, 0.f, 0.f};
        p = MFMA(a0, b0, p);
        p = MFMA(a1, b1, p);
        // ISM dropped: phi_k scale cancels exactly in out = qf*ktv / (qf*ksum)
        const float e0 = exp2f(fmaf(SC2, p[0], -sqv[0]));
        const float e1 = exp2f(fmaf(SC2, p[1], -sqv[1]));
        const float e2 = exp2f(fmaf(SC2, p[2], -sqv[2]));
        const float e3 = exp2f(fmaf(SC2, p[3], -sqv[3]));
        uint2 pk;
        pk.x = (unsigned)f2b(e0) | ((unsigned)f2b(e1) << 16);
        pk.y = (unsigned)f2b(e2) | ((unsigned)f2b(e3) << 16);
        const int bytn = 32 * ntile + 8 * kg;
        *(uint2*)(kfT_b + mloc * 128 + (bytn ^ ((mloc & 7) << 4))) = pk;
      }
    }
    __syncthreads();  // kfT visible; all waves done reading k_s(ch)
    if (ch < 3) {     // issue next chunk's k DMA + v reg-load; hide under GEMM2
      stage_k(ch + 1);
      vreg = load_v(ch + 1);
    }
    const char* vt_cur = (const char*)vt[ch & 1];
    if (cg == 0)
      s2_gemm2<3, 0>(kfT_b, vt_cur, mts, ln, kg, acc);
    else
      s2_gemm2<2, 3>(kfT_b, vt_cur, mts, ln, kg, acc);
    if (ch < 3) scat_v(vreg, (ch + 1) & 1);  // other buffer; overlaps GEMM2 tail
    __syncthreads();  // drains vmcnt: k_s(ch+1) landed; vt[(ch+1)&1] visible
  }
  // write partials
  float* base = ktv_part + ((size_t)ng * 48 + bh) * (384 * 64);
  const int nct2 = cg ? 2 : 3, ct0c = cg ? 3 : 0;
#pragma unroll
  for (int j = 0; j < 3; ++j)
#pragma unroll
    for (int i = 0; i < 3; ++i) {
      if (i >= nct2) continue;
      const int ct = ct0c + i;
      const int mrow0 = m0 + (mts + j) * 16 + kg * 4;
      if (ct < 4) {
        const int c = ct * 16 + ln;
#pragma unroll
        for (int r = 0; r < 4; ++r) base[(size_t)(mrow0 + r) * 64 + c] = acc[j][i][r];
      } else if (ln == 0) {
#pragma unroll
        for (int r = 0; r < 4; ++r)
          ksum_part[((size_t)ng * 48 + bh) * 384 + mrow0 + r] = acc[j][i][r];
      }
    }
}

// ---------- reduction over the 8 n-groups -> ktv_ext [bh][80][384] bf16 ----------
// grid: [0,288) ktv 64x64 transpose-reduce tiles | [288,360) ksum hi/lo
__global__ __launch_bounds__(256) void reduce_all_k(const float* __restrict__ part,
                                                    const float* __restrict__ partk,
                                                    unsigned short* __restrict__ ktve) {
  __shared__ float lds[64 * 65];
  const int bid = blockIdx.x;
  const int t = threadIdx.x;
  if (bid < 288) {
    const int bh = bid / 6, m0 = (bid % 6) * 64;
    const size_t gs = (size_t)48 * 24576;
    const int c = t & 63, mr = t >> 6;  // wave-uniform m, lane-contiguous c -> coalesced reads
#pragma unroll
    for (int p = 0; p < 16; ++p) {
      const int m = p * 4 + mr;
      const size_t o = ((size_t)bh * 384 + m0 + m) * 64 + c;
      float s = 0.f;
#pragma unroll
      for (int g = 0; g < 8; ++g) s += part[o + (size_t)g * gs];
      lds[c * 65 + m] = s;  // (65c+m)%32 = (c+m)%32 -> 2-way max, free
    }
    __syncthreads();
    const int cr = t >> 2, mq = (t & 3) * 16;
    s16x8 o0, o1;
#pragma unroll
    for (int j = 0; j < 8; ++j) {
      o0[j] = (short)f2b(lds[cr * 65 + mq + j]);
      o1[j] = (short)f2b(lds[cr * 65 + mq + 8 + j]);
    }
    unsigned short* dst = ktve + ((size_t)bh * 80 + cr) * 384 + m0 + mq;
    *(s16x8*)dst = o0;          // m-contiguous 32B/lane -> coalesced writes
    *(s16x8*)(dst + 8) = o1;
  } else {
    const int idx = (bid - 288) * 256 + t;  // 48*384
    const int bh = idx / 384, m = idx % 384;
    const int gk = 48 * 384;
    float s = 0.f;
#pragma unroll
    for (int g = 0; g < 8; ++g) s += partk[idx + g * gk];
    const unsigned short hi = f2b(s);
    const unsigned short lo = f2b(s - b2f(hi));
    const size_t base = ((size_t)bh * 80 + 64) * 384 + m;
    ktve[base] = hi;
    ktve[base + 384] = lo;
  }
}

// ---------- stage 3: fused phi(q)+attn; SINGLE-buffer wt/kt (49.25KB -> 3 blocks/CU,
// 768-block one-round fit; inter-block overlap replaces dbuf per r6/r8/r13 lesson) ----------
// grid (16, H, B), 512 threads; 128 tokens/block; 6 m-chunks of 64
__global__ __launch_bounds__(512, 4) void stage3_k(const unsigned short* __restrict__ qkv,
                                                   const unsigned short* __restrict__ wt,
                                                   const unsigned short* __restrict__ ktve,
                                                   unsigned short* __restrict__ attn) {
  __shared__ unsigned short q_s[128 * 64];   // [tok][c] swizzled, 16KB
  __shared__ unsigned short qf_s[128 * 64];  // [tok][m_chunk] swizzled, wave-private rows
  __shared__ unsigned short wt_s[64 * 64];   // [m][c] swizzled, 8KB
  __shared__ unsigned short kt_s[72 * 64];   // [cext][m_chunk] swizzled, 9KB (rows 0-71)
  char* q_b = (char*)q_s;
  char* qf_b = (char*)qf_s;
  const int t = threadIdx.x, lane = t & 63, w = t >> 6;
  const int ln = lane & 15, kg = lane >> 4;
  const int nb = blockIdx.x, h = blockIdx.y, b = blockIdx.z, bh = b * Hn + h;
  const size_t tok0 = (size_t)b * Nn + nb * 128;
  const int lr = lane >> 3, sl = lane & 7;

  // stage q tile (128 rows x 128B), 2 gl_lds16 per wave
#pragma unroll
  for (int rr = 0; rr < 2; ++rr) {
    const int row = w * 16 + rr * 8 + lr;
    gl_lds16(qkv + (tok0 + row) * 2304 + h * 64 + ((sl ^ (row & 7)) * 8),
             q_s + (w * 16 + rr * 8) * 64 + lane * 8);
  }
  // chunk stagers (single buffer)
  auto stage_wt = [&](int mc) {
    const int row = w * 8 + lr;
    gl_lds16(wt + ((size_t)h * 384 + mc * 64 + row) * 64 + ((sl ^ (row & 7)) * 8),
             wt_s + w * 512 + lane * 8);
  };
  auto stage_kt = [&](int mc) {
    const int row = w * 8 + lr;
    gl_lds16(ktve + ((size_t)bh * 80 + row) * 384 + mc * 64 + ((sl ^ (row & 7)) * 8),
             kt_s + w * 512 + lane * 8);
    if (w == 0) {  // rows 64-71: hi/lo normalizer rows (cols 66-79 unconsumed)
      const int row2 = 64 + lr;
      gl_lds16(ktve + ((size_t)bh * 80 + row2) * 384 + mc * 64 + ((sl ^ (row2 & 7)) * 8),
               kt_s + 64 * 64 + lane * 8);
    }
  };

  f32x4 acc2[5];
#pragma unroll
  for (int i = 0; i < 5; ++i) acc2[i] = (f32x4){0.f, 0.f, 0.f, 0.f};

  const int arow = w * 16 + ln;          // this wave's A-row (token) for both GEMMs
  const char* qrow = q_b + arow * 128;
  const int asw = (arow & 7) << 4;

  for (int mc = 0; mc < 6; ++mc) {
    __syncthreads();  // all waves done reading wt_s/kt_s(mc-1) before overwrite
    stage_wt(mc);
    stage_kt(mc);
    __syncthreads();  // barrier drains vmcnt -> wt/kt(mc) visible (q too on mc=0)
    // GEMM1: proj[tok 16][m 64] for this wave's token tile
    const s16x8 af0 = *(const s16x8*)(qrow + ((kg << 4) ^ asw));
    const s16x8 af1 = *(const s16x8*)(qrow + (((kg + 4) << 4) ^ asw));
    const char* wb = (const char*)wt_s;
    f32x4 p[4];
#pragma unroll
    for (int mt = 0; mt < 4; ++mt) {
      const int mrow = mt * 16 + ln;
      const s16x8 b0 = *(const s16x8*)(wb + mrow * 128 + ((kg ^ (mrow & 7)) << 4));
      const s16x8 b1 = *(const s16x8*)(wb + mrow * 128 + (((kg + 4) ^ (mrow & 7)) << 4));
      f32x4 pp = (f32x4){0.f, 0.f, 0.f, 0.f};
      pp = MFMA(af0, b0, pp);
      p[mt] = MFMA(af1, b1, pp);
    }
    // exp2 -> qf (wave-private rows; sq_q and ISM cancel in num/D)
#pragma unroll
    for (int mt = 0; mt < 4; ++mt) {
#pragma unroll
      for (int r = 0; r < 4; ++r) {
        const int trow = w * 16 + kg * 4 + r;
        const int m = mt * 16 + ln;
        *(unsigned short*)(qf_b + trow * 128 + ((2 * m) ^ ((trow & 7) << 4))) =
            f2b(exp2f(SC2 * p[mt][r]));
      }
    }
    // GEMM2: acc2 += qf(tile) @ kt^T  (same-wave LDS dep only; no barrier)
    const char* qfr = qf_b + arow * 128;
    const s16x8 a0 = *(const s16x8*)(qfr + ((kg << 4) ^ asw));
    const s16x8 a1 = *(const s16x8*)(qfr + (((kg + 4) << 4) ^ asw));
    const char* kb = (const char*)kt_s;
#pragma unroll
    for (int ct = 0; ct < 5; ++ct) {
      const int crow = ct * 16 + ln;
      const s16x8 b0 = *(const s16x8*)(kb + crow * 128 + ((kg ^ (crow & 7)) << 4));
      const s16x8 b1 = *(const s16x8*)(kb + crow * 128 + (((kg + 4) ^ (crow & 7)) << 4));
      acc2[ct] = MFMA(a0, b0, acc2[ct]);
      acc2[ct] = MFMA(a1, b1, acc2[ct]);
    }
  }
  // D from c-tile 4 (cols 64=hi, 65=lo) via shuffles; tokens match acc rows
  float dv[4];
#pragma unroll
  for (int r = 0; r < 4; ++r) {
    const float hi = __shfl(acc2[4][r], (lane & 48));
    const float lo = __shfl(acc2[4][r], (lane & 48) | 1);
    dv[r] = 1.0f / (hi + lo + EPS);
  }
#pragma unroll
  for (int ct = 0; ct < 4; ++ct) {
#pragma unroll
    for (int r = 0; r < 4; ++r) {
      const int trow = w * 16 + kg * 4 + r;
      const int c = ct * 16 + ln;
      attn[(tok0 + trow) * 768 + h * 64 + c] = f2b(acc2[ct][r] * dv[r]);
    }
  }
}

}  // namespace

extern "C" void kernel_launch(void* const* d_in, const int* in_sizes, int n_in,
                              void* d_out, int out_size, void* d_ws, size_t ws_size,
                              hipStream_t stream) {
  const float* x = (const float*)d_in[0];
  const float* w = (const float*)d_in[1];
  const float* Wqkv = (const float*)d_in[2];
  const float* Wproj = (const float*)d_in[3];
  const float* bproj = (const float*)d_in[4];

  char* ws = (char*)d_ws;
  // region0 (aliased): [xb 12,582,912 | wqT 3,538,944] vs [ktv_part 37,748,736 | ksum_part 589,824]
  unsigned short* xb = (unsigned short*)(ws);
  unsigned short* wqT = (unsigned short*)(ws + 12582912);
  float* ktv_part = (float*)(ws);
  float* ksum_part = (float*)(ws + 37748736);
  char* p = ws + 38338560;
  unsigned short* qkvb = (unsigned short*)p;  p += 37748736;   // (8192,2304) bf16
  unsigned short* wt = (unsigned short*)p;    p += 589824;     // (12,384,64) bf16
  unsigned short* ktve = (unsigned short*)p;  p += 2949120;    // (48,80,384) bf16
  unsigned short* attn = (unsigned short*)p;  p += 12582912;   // (8192,768) bf16
  unsigned short* wpT = (unsigned short*)p;                    // (768,768) bf16

  cvt_all_k<<<3720, 256, 0, stream>>>(x, Wqkv, Wproj, w, xb, wqT, wpT, wt);
  gemm_qkv_k<<<dim3(18, 64), 256, 0, stream>>>(xb, wqT, qkvb);
  stage2_k<<<dim3(16, 12, 4), 512, 0, stream>>>(qkvb, wt, ktv_part, ksum_part);
  reduce_all_k<<<360, 256, 0, stream>>>(ktv_part, ksum_part, ktve);
  stage3_k<<<dim3(16, 12, 4), 512, 0, stream>>>(qkvb, wt, ktve, attn);
  gemm_proj_k<<<dim3(12, 64), 256, 0, stream>>>(attn, wpT, (float*)d_out, bproj);
}